// Round 1
// baseline (9425.578 us; speedup 1.0000x reference)
//
#include <hip/hip_runtime.h>

// ---------------------------------------------------------------------------
// MoE forward: CNN trunk (fp32 direct conv) + per-expert heads + capacity-
// constrained iterative routing + weighted combine.
// ---------------------------------------------------------------------------

__global__ __launch_bounds__(256) void bnprep_kernel(
    const float* __restrict__ g, const float* __restrict__ be,
    const float* __restrict__ m, const float* __restrict__ v,
    const float* __restrict__ b, float* __restrict__ A, float* __restrict__ C, int n)
{
  int i = blockIdx.x * 256 + threadIdx.x;
  if (i < n) {
    float s = g[i] / sqrtf(v[i] + 1e-5f);
    A[i] = s;
    C[i] = (b[i] - m[i]) * s + be[i];
  }
}

// Direct 3x3 SAME conv + folded BN + ReLU, optional fused 2x2 maxpool,
// optional fused global-average-pool (writes feats with stride 256).
// Tile: 16x16 spatial x COT channels per block (256 threads).
// Thread: 4 pixels (rows r0+4i, col xx) x NCO=COT/4 channels.
template<int CI, int CO, int COT, int HH, int WW, int POOL, int CICH, int AVG>
__global__ __launch_bounds__(256) void conv3x3_kernel(
    const float* __restrict__ in, const float* __restrict__ wgt,
    const float* __restrict__ Ap, const float* __restrict__ Cp,
    float* __restrict__ out)
{
  constexpr int SIN = CICH * 324;       // CICH x 18 x 18
  constexpr int SW  = CICH * 9 * COT;
  constexpr int NCO = COT / 4;
  constexpr int CT  = CO / COT;
  __shared__ alignas(16) float smem[SIN + SW];

  const int tid = threadIdx.x;
  const int img = blockIdx.x / CT;
  const int coBase = (blockIdx.x % CT) * COT;
  constexpr int TILESX = WW / 16;
  const int by = (blockIdx.y / TILESX) * 16;
  const int bx = (blockIdx.y % TILESX) * 16;

  const int lane = tid & 63;
  const int r0 = (tid & 63) >> 4;   // 0..3
  const int xx = tid & 15;          // 0..15
  const int cog = tid >> 6;         // wave id 0..3

  float acc[4][NCO];
  #pragma unroll
  for (int i = 0; i < 4; ++i)
    #pragma unroll
    for (int j = 0; j < NCO; ++j) acc[i][j] = 0.f;

  const long inImgOff = (long)img * CI * (HH * WW);

  for (int cb = 0; cb < CI; cb += CICH) {
    __syncthreads();
    // stage input tile with halo (zero padded)
    for (int e2 = tid; e2 < SIN; e2 += 256) {
      int ci = e2 / 324;
      int rem = e2 - ci * 324;
      int rr = rem / 18;
      int cc = rem - rr * 18;
      int gy = by + rr - 1, gx = bx + cc - 1;
      float vL = 0.f;
      if (gy >= 0 && gy < HH && gx >= 0 && gx < WW)
        vL = in[inImgOff + (long)(cb + ci) * (HH * WW) + gy * WW + gx];
      smem[e2] = vL;
    }
    // stage weights [ci][k][co]
    for (int e2 = tid; e2 < SW; e2 += 256) {
      int co = e2 % COT;
      int k  = (e2 / COT) % 9;
      int ci = e2 / (COT * 9);
      smem[SIN + e2] = wgt[((long)(coBase + co) * CI + cb + ci) * 9 + k];
    }
    __syncthreads();
    for (int ci = 0; ci < CICH; ++ci) {
      const float* sI = smem + ci * 324;
      #pragma unroll
      for (int k = 0; k < 9; ++k) {
        const int ky = k / 3, kx = k - 3 * (k / 3);
        const float4* w4 = (const float4*)(smem + SIN + (ci * 9 + k) * COT + cog * NCO);
        float4 wv[NCO / 4];
        #pragma unroll
        for (int q = 0; q < NCO / 4; ++q) wv[q] = w4[q];
        float iv[4];
        #pragma unroll
        for (int i = 0; i < 4; ++i) iv[i] = sI[(r0 + 4 * i + ky) * 18 + xx + kx];
        #pragma unroll
        for (int i = 0; i < 4; ++i) {
          #pragma unroll
          for (int q = 0; q < NCO / 4; ++q) {
            acc[i][4 * q + 0] += iv[i] * wv[q].x;
            acc[i][4 * q + 1] += iv[i] * wv[q].y;
            acc[i][4 * q + 2] += iv[i] * wv[q].z;
            acc[i][4 * q + 3] += iv[i] * wv[q].w;
          }
        }
      }
    }
  }
  __syncthreads();

  if (POOL == 1) {
    #pragma unroll
    for (int j = 0; j < NCO; ++j) {
      int co = coBase + cog * NCO + j;
      float Ar = Ap[co], Cr = Cp[co];
      #pragma unroll
      for (int i = 0; i < 4; ++i) {
        float vO = fmaxf(acc[i][j] * Ar + Cr, 0.f);
        out[((long)img * CO + co) * (HH * WW) + (by + r0 + 4 * i) * WW + bx + xx] = vO;
      }
    }
  } else {
    // fused 2x2 maxpool via cross-lane max
    #pragma unroll
    for (int j = 0; j < NCO; ++j) {
      int co = coBase + cog * NCO + j;
      float Ar = Ap[co], Cr = Cp[co];
      #pragma unroll
      for (int i = 0; i < 4; ++i) {
        float vO = fmaxf(acc[i][j] * Ar + Cr, 0.f);
        float h1 = fmaxf(vO, __shfl_xor(vO, 1));
        float p  = fmaxf(h1, __shfl_xor(h1, 16));
        if ((lane & 17) == 0) {
          int prow = 2 * i + (lane >> 5);
          int pcol = (lane & 15) >> 1;
          if (AVG) {
            smem[(cog * NCO + j) * 65 + prow * 8 + pcol] = p;
          } else {
            out[((long)img * CO + co) * ((HH / 2) * (WW / 2))
                + ((by >> 1) + prow) * (WW / 2) + (bx >> 1) + pcol] = p;
          }
        }
      }
    }
    if (AVG) {
      // global average pool over the 8x8 pooled map -> feats[img][coBase+co]
      __syncthreads();
      int co = tid & 63, q = tid >> 6;
      float s = 0.f;
      #pragma unroll
      for (int p2 = 0; p2 < 16; ++p2) s += smem[co * 65 + q * 16 + p2];
      smem[COT * 65 + q * COT + co] = s;
      __syncthreads();
      if (tid < COT) {
        float s2 = smem[COT * 65 + tid] + smem[COT * 65 + COT + tid]
                 + smem[COT * 65 + 2 * COT + tid] + smem[COT * 65 + 3 * COT + tid];
        out[(long)img * 256 + coBase + tid] = s2 * (1.f / 64.f);
      }
    }
  }
}

// Per-expert heads: gate MLP score + classifier logits + softmax entropy ->
// routing score. One block = 16 tokens x 1 expert.
__global__ __launch_bounds__(256) void heads_kernel(
    const float* __restrict__ feats, const float* __restrict__ gw1,
    const float* __restrict__ gb1, const float* __restrict__ gw2,
    const float* __restrict__ gb2, const float* __restrict__ clsw,
    const float* __restrict__ clsb, const float* __restrict__ usage,
    float* __restrict__ logits_e, float* __restrict__ rs_out)
{
  __shared__ float sF[16][257];
  __shared__ alignas(16) float sU[8192];   // gw1 chunk [64][128]
  __shared__ alignas(16) float sC[10][256];
  __shared__ float sRed[16][17];
  __shared__ float sL[16][10];
  __shared__ float sEs[16];
  const int tid = threadIdx.x;
  const int b0 = blockIdx.x * 16;
  const int e = blockIdx.y;

  for (int idx = tid; idx < 16 * 256; idx += 256) {
    int t = idx >> 8, d = idx & 255;
    sF[t][d] = feats[(long)(b0 + t) * 256 + d];
  }
  for (int idx = tid; idx < 10 * 256; idx += 256) {
    int c = idx >> 8, d = idx & 255;
    sC[c][d] = clsw[((long)e * 10 + c) * 256 + d];
  }
  const int t = tid & 15, hg = tid >> 4;   // 16 tokens x 16 h-groups of 8
  float acc[8];
  #pragma unroll
  for (int q = 0; q < 8; ++q) acc[q] = 0.f;
  for (int dc = 0; dc < 4; ++dc) {
    __syncthreads();
    for (int idx = tid; idx < 8192; idx += 256) {
      int dd = idx >> 7, h = idx & 127;
      sU[dd * 128 + h] = gw1[((long)e * 256 + dc * 64 + dd) * 128 + h];
    }
    __syncthreads();
    for (int dd = 0; dd < 64; ++dd) {
      float f = sF[t][dc * 64 + dd];
      const float4* w4 = (const float4*)(sU + dd * 128 + hg * 8);
      float4 w0 = w4[0], w1 = w4[1];
      acc[0] += f * w0.x; acc[1] += f * w0.y; acc[2] += f * w0.z; acc[3] += f * w0.w;
      acc[4] += f * w1.x; acc[5] += f * w1.y; acc[6] += f * w1.z; acc[7] += f * w1.w;
    }
  }
  {
    float s = 0.f;
    #pragma unroll
    for (int q = 0; q < 8; ++q) {
      int h = hg * 8 + q;
      float hid = fmaxf(acc[q] + gb1[e * 128 + h], 0.f);
      s += hid * gw2[e * 128 + h];
    }
    sRed[t][hg] = s;
  }
  __syncthreads();
  if (tid < 16) {
    float s = 0.f;
    #pragma unroll
    for (int q = 0; q < 16; ++q) s += sRed[tid][q];
    sEs[tid] = (s + gb2[e]) * 0.5f;   // / DTEMP
  }
  if (tid < 160) {
    int tt = tid & 15, c = tid >> 4;
    float s = 0.f;
    for (int d = 0; d < 256; ++d) s += sF[tt][d] * sC[c][d];
    sL[tt][c] = s + clsb[e * 10 + c];
  }
  __syncthreads();
  if (tid < 16) {
    float mx = sL[tid][0];
    #pragma unroll
    for (int c = 1; c < 10; ++c) mx = fmaxf(mx, sL[tid][c]);
    float S = 0.f, ps[10];
    #pragma unroll
    for (int c = 0; c < 10; ++c) { ps[c] = expf(sL[tid][c] - mx); S += ps[c]; }
    float inv = 1.f / S, ent = 0.f;
    #pragma unroll
    for (int c = 0; c < 10; ++c) { float p = ps[c] * inv; ent -= p * logf(fmaxf(p, 1e-12f)); }
    float rsv = 0.6f * sEs[tid] + 0.4f * (-ent) - 2.0f * usage[e];
    rs_out[(long)(b0 + tid) * 16 + e] = rsv;
  }
  if (tid < 160) {
    int tt = tid & 15, c = tid >> 4;
    logits_e[((long)(b0 + tt) * 16 + e) * 10 + c] = sL[tt][c];
  }
}

// Per-expert descending argsort of routing scores (ties: lower index first).
__global__ __launch_bounds__(1024) void sort_kernel(
    const float* __restrict__ rs, unsigned* __restrict__ sortedIdx)
{
  __shared__ unsigned long long sk[2048];
  const int e = blockIdx.x;
  const unsigned tid = threadIdx.x;
  for (int i = tid; i < 2048; i += 1024) {
    float f = rs[(long)i * 16 + e];
    unsigned u = __float_as_uint(f);
    u ^= (u >> 31) ? 0xFFFFFFFFu : 0x80000000u;   // monotone map
    sk[i] = ((unsigned long long)(~u) << 32) | (unsigned)i; // asc sort == desc score, asc idx
  }
  for (unsigned k = 2; k <= 2048; k <<= 1) {
    for (unsigned j = k >> 1; j > 0; j >>= 1) {
      __syncthreads();
      unsigned i = ((tid & ~(j - 1)) << 1) | (tid & (j - 1));
      unsigned p = i | j;
      bool asc = ((i & k) == 0);
      unsigned long long a = sk[i], b = sk[p];
      if ((a > b) == asc) { sk[i] = b; sk[p] = a; }
    }
  }
  __syncthreads();
  for (int i = tid; i < 2048; i += 1024)
    sortedIdx[(long)e * 2048 + i] = (unsigned)(sk[i] & 0xFFFFFFFFull);
}

// Sequential capacity-constrained routing + fallback, single block.
__global__ __launch_bounds__(1024) void routing_kernel(
    const unsigned* __restrict__ sortedIdx, const float* __restrict__ rs,
    float* __restrict__ Dout, unsigned* __restrict__ dmaskOut)
{
  __shared__ unsigned char sAvail[2048];
  __shared__ unsigned sDm[2048];
  __shared__ int sLoads[16];
  __shared__ int sWaveCnt[16];
  __shared__ int sNtc, sVC;
  const int tid = threadIdx.x;
  const int lane = tid & 63, wave = tid >> 6;
  for (int i = tid; i < 2048; i += 1024) { sAvail[i] = 1; sDm[i] = 0; }
  if (tid < 16) sLoads[tid] = 0;
  if (tid == 0) sVC = 2048;
  __syncthreads();
  for (int it = 0; it < 3; ++it) {
    for (int j = 0; j < 16; ++j) {
      if (tid == 0) {
        int rc = 256 - sLoads[j]; if (rc < 0) rc = 0;
        int vc = sVC, ntc = 0;
        if (rc > 0 && vc > 0) {
          int a = rc < vc ? rc : vc;
          int b2 = vc < 102 ? vc : 102;
          ntc = a > b2 ? a : b2;
        }
        sNtc = ntc; sLoads[j] += ntc; sVC -= ntc;
      }
      __syncthreads();
      const int ntc = sNtc;
      if (ntc > 0) {
        int base = 0;
        for (int p = 0; p < 2; ++p) {
          int i = p * 1024 + tid;
          unsigned tok = sortedIdx[(long)j * 2048 + i];
          int fl = sAvail[tok] ? 1 : 0;
          unsigned long long bm = __ballot(fl);
          if (lane == 0) sWaveCnt[wave] = __popcll(bm);
          __syncthreads();
          int off = base;
          for (int w = 0; w < wave; ++w) off += sWaveCnt[w];
          int pre = off + __popcll(bm & ((1ull << lane) - 1ull));
          if (fl && pre < ntc) { sAvail[tok] = 0; sDm[tok] |= (1u << j); }
          int tot = base;
          for (int w = 0; w < 16; ++w) tot += sWaveCnt[w];
          base = tot;
          __syncthreads();
        }
      }
      __syncthreads();
    }
  }
  // fallback: least-loaded of per-token top-3 (sequential, usually 0 tokens)
  if (tid == 0 && sVC > 0) {
    for (int i = 0; i < 2048; ++i) {
      if (!sAvail[i]) continue;
      float s0 = -3.4e38f, s1 = s0, s2 = s0; int e0 = 0, e1 = 0, e2 = 0;
      for (int e = 0; e < 16; ++e) {
        float s = rs[i * 16 + e];
        if (s > s0)      { s2 = s1; e2 = e1; s1 = s0; e1 = e0; s0 = s; e0 = e; }
        else if (s > s1) { s2 = s1; e2 = e1; s1 = s;  e1 = e; }
        else if (s > s2) { s2 = s;  e2 = e; }
      }
      int best = e0, bl = sLoads[e0];
      if (sLoads[e1] < bl) { best = e1; bl = sLoads[e1]; }
      if (sLoads[e2] < bl) { best = e2; bl = sLoads[e2]; }
      sDm[i] |= (1u << best);
      sLoads[best] += 1;
    }
  }
  __syncthreads();
  for (int idx = tid; idx < 2048 * 16; idx += 1024) {
    int tok = idx >> 4, e = idx & 15;
    Dout[idx] = ((sDm[tok] >> e) & 1u) ? 1.0f : 0.0f;
  }
  for (int i = tid; i < 2048; i += 1024) dmaskOut[i] = sDm[i];
}

__global__ __launch_bounds__(256) void combine_kernel(
    const unsigned* __restrict__ dmask, const float* __restrict__ rs,
    const float* __restrict__ L, float* __restrict__ out)
{
  int i = blockIdx.x * 256 + threadIdx.x;
  if (i >= 2048) return;
  unsigned dm = dmask[i];
  float r[16];
  #pragma unroll
  for (int e = 0; e < 16; ++e) r[e] = rs[i * 16 + e];
  float mx = -3.4e38f;
  #pragma unroll
  for (int e = 0; e < 16; ++e) {
    float v = ((dm >> e) & 1u) ? r[e] : 0.0f;   // matches active = rs * D, max incl. zeros
    mx = fmaxf(mx, v);
  }
  float w[16], S = 0.f;
  #pragma unroll
  for (int e = 0; e < 16; ++e) {
    w[e] = ((dm >> e) & 1u) ? expf(r[e] - mx) : 0.0f;
    S += w[e];
  }
  float inv = 1.f / S;
  #pragma unroll
  for (int c = 0; c < 10; ++c) {
    float a = 0.f;
    #pragma unroll
    for (int e = 0; e < 16; ++e) a += w[e] * L[((long)i * 16 + e) * 10 + c];
    out[i * 10 + c] = a * inv;
  }
}

extern "C" void kernel_launch(void* const* d_in, const int* in_sizes, int n_in,
                              void* d_out, int out_size, void* d_ws, size_t ws_size,
                              hipStream_t stream)
{
  const float* x    = (const float*)d_in[0];
  const float* cw1  = (const float*)d_in[1];
  const float* cb1  = (const float*)d_in[2];
  const float* g1   = (const float*)d_in[3];
  const float* be1  = (const float*)d_in[4];
  const float* m1   = (const float*)d_in[5];
  const float* v1   = (const float*)d_in[6];
  const float* cw2  = (const float*)d_in[7];
  const float* cb2  = (const float*)d_in[8];
  const float* g2   = (const float*)d_in[9];
  const float* be2  = (const float*)d_in[10];
  const float* m2   = (const float*)d_in[11];
  const float* v2   = (const float*)d_in[12];
  const float* cw3  = (const float*)d_in[13];
  const float* cb3  = (const float*)d_in[14];
  const float* g3   = (const float*)d_in[15];
  const float* be3  = (const float*)d_in[16];
  const float* m3   = (const float*)d_in[17];
  const float* v3   = (const float*)d_in[18];
  const float* cw4  = (const float*)d_in[19];
  const float* cb4  = (const float*)d_in[20];
  const float* g4   = (const float*)d_in[21];
  const float* be4  = (const float*)d_in[22];
  const float* m4   = (const float*)d_in[23];
  const float* v4   = (const float*)d_in[24];
  const float* gw1  = (const float*)d_in[25];
  const float* gb1  = (const float*)d_in[26];
  const float* gw2  = (const float*)d_in[27];
  const float* gb2  = (const float*)d_in[28];
  const float* clsw = (const float*)d_in[29];
  const float* clsb = (const float*)d_in[30];
  const float* usage = (const float*)d_in[31];

  float* out = (float*)d_out;
  float* ws  = (float*)d_ws;

  // workspace layout (floats)
  float* A1 = ws + 0;   float* C1 = ws + 32;
  float* A2 = ws + 64;  float* C2 = ws + 128;
  float* A3 = ws + 192; float* C3 = ws + 320;
  float* A4 = ws + 448; float* C4 = ws + 704;
  float* feats   = ws + 1024;                       // 2048*256
  float* logitsE = ws + 1024 + 524288;              // 2048*16*10
  unsigned* sortedIdx = (unsigned*)(ws + 852992);   // 16*2048
  unsigned* dmask     = (unsigned*)(ws + 885760);   // 2048
  float* bufBase = ws + 887808;

  long wsFloats = (long)(ws_size / 4);
  long availF = wsFloats - 887808;
  long chunkL = availF / 49152;                     // 32768 (bufA) + 16384 (bufB) per image
  int chunk = (int)(chunkL < 1 ? 1 : (chunkL > 2048 ? 2048 : chunkL));

  bnprep_kernel<<<1, 256, 0, stream>>>(g1, be1, m1, v1, cb1, A1, C1, 32);
  bnprep_kernel<<<1, 256, 0, stream>>>(g2, be2, m2, v2, cb2, A2, C2, 64);
  bnprep_kernel<<<1, 256, 0, stream>>>(g3, be3, m3, v3, cb3, A3, C3, 128);
  bnprep_kernel<<<1, 256, 0, stream>>>(g4, be4, m4, v4, cb4, A4, C4, 256);

  float* bufA = bufBase;
  float* bufB = bufBase + (long)chunk * 32768;

  for (int ib = 0; ib < 2048; ib += chunk) {
    int n = 2048 - ib; if (n > chunk) n = chunk;
    conv3x3_kernel<3, 32, 32, 32, 32, 1, 3, 0>
        <<<dim3(n, 4), 256, 0, stream>>>(x + (long)ib * 3072, cw1, A1, C1, bufA);
    conv3x3_kernel<32, 64, 64, 32, 32, 2, 16, 0>
        <<<dim3(n, 4), 256, 0, stream>>>(bufA, cw2, A2, C2, bufB);
    conv3x3_kernel<64, 128, 64, 16, 16, 1, 16, 0>
        <<<dim3(n * 2, 1), 256, 0, stream>>>(bufB, cw3, A3, C3, bufA);
    conv3x3_kernel<128, 256, 64, 16, 16, 2, 16, 1>
        <<<dim3(n * 4, 1), 256, 0, stream>>>(bufA, cw4, A4, C4, feats + (long)ib * 256);
  }

  float* rsOut = out + 20480;   // routing_scores region [2048,16]
  heads_kernel<<<dim3(128, 16), 256, 0, stream>>>(feats, gw1, gb1, gw2, gb2,
                                                  clsw, clsb, usage, logitsE, rsOut);
  sort_kernel<<<16, 1024, 0, stream>>>(rsOut, sortedIdx);
  routing_kernel<<<1, 1024, 0, stream>>>(sortedIdx, rsOut, out + 53248, dmask);
  combine_kernel<<<8, 256, 0, stream>>>(dmask, rsOut, logitsE, out);
}

// Round 2
// 7343.708 us; speedup vs baseline: 1.2835x; 1.2835x over previous
//
#include <hip/hip_runtime.h>

// ---------------------------------------------------------------------------
// MoE forward: CNN trunk (fp32 direct conv) + per-expert heads + capacity-
// constrained iterative routing + weighted combine.
// ---------------------------------------------------------------------------

__global__ __launch_bounds__(256) void bnprep_kernel(
    const float* __restrict__ g, const float* __restrict__ be,
    const float* __restrict__ m, const float* __restrict__ v,
    const float* __restrict__ b, float* __restrict__ A, float* __restrict__ C, int n)
{
  int i = blockIdx.x * 256 + threadIdx.x;
  if (i < n) {
    float s = g[i] / sqrtf(v[i] + 1e-5f);
    A[i] = s;
    C[i] = (b[i] - m[i]) * s + be[i];
  }
}

// Direct 3x3 SAME conv + folded BN + ReLU, optional fused 2x2 maxpool,
// optional fused global-average-pool (writes feats with stride 256).
// Input tile staged with halo at row stride 24 -> all LDS reads exactly
// 2-way bank aliased (free on CDNA4).
template<int CI, int CO, int COT, int HH, int WW, int POOL, int CICH, int AVG>
__global__ __launch_bounds__(256) void conv3x3_kernel(
    const float* __restrict__ in, const float* __restrict__ wgt,
    const float* __restrict__ Ap, const float* __restrict__ Cp,
    float* __restrict__ out)
{
  constexpr int RS   = 24;              // padded row stride (banks: exact 2-way)
  constexpr int SINP = CICH * 18 * RS;  // input tile region (floats)
  constexpr int SW   = CICH * 9 * COT;
  constexpr int NCO  = COT / 4;
  constexpr int CT   = CO / COT;
  __shared__ alignas(16) float smem[SINP + SW];

  const int tid = threadIdx.x;
  const int img = blockIdx.x / CT;
  const int coBase = (blockIdx.x % CT) * COT;
  constexpr int TILESX = WW / 16;
  const int by = (blockIdx.y / TILESX) * 16;
  const int bx = (blockIdx.y % TILESX) * 16;

  const int lane = tid & 63;
  const int r0 = (tid & 63) >> 4;   // 0..3
  const int xx = tid & 15;          // 0..15
  const int cog = tid >> 6;         // wave id 0..3

  float acc[4][NCO];
  #pragma unroll
  for (int i = 0; i < 4; ++i)
    #pragma unroll
    for (int j = 0; j < NCO; ++j) acc[i][j] = 0.f;

  const long inImgOff = (long)img * CI * (HH * WW);

  for (int cb = 0; cb < CI; cb += CICH) {
    __syncthreads();
    // stage input tile with halo (zero padded)
    for (int e2 = tid; e2 < CICH * 324; e2 += 256) {
      int ci = e2 / 324;
      int rem = e2 - ci * 324;
      int rr = rem / 18;
      int cc = rem - rr * 18;
      int gy = by + rr - 1, gx = bx + cc - 1;
      float vL = 0.f;
      if (gy >= 0 && gy < HH && gx >= 0 && gx < WW)
        vL = in[inImgOff + (long)(cb + ci) * (HH * WW) + gy * WW + gx];
      smem[ci * (18 * RS) + rr * RS + cc] = vL;
    }
    // stage weights [ci][k][co]
    for (int e2 = tid; e2 < SW; e2 += 256) {
      int co = e2 % COT;
      int k  = (e2 / COT) % 9;
      int ci = e2 / (COT * 9);
      smem[SINP + e2] = wgt[((long)(coBase + co) * CI + cb + ci) * 9 + k];
    }
    __syncthreads();
    for (int ci = 0; ci < CICH; ++ci) {
      const float* sI = smem + ci * (18 * RS);
      #pragma unroll
      for (int k = 0; k < 9; ++k) {
        const int ky = k / 3, kx = k - 3 * (k / 3);
        const float4* w4 = (const float4*)(smem + SINP + (ci * 9 + k) * COT + cog * NCO);
        float4 wv[NCO / 4];
        #pragma unroll
        for (int q = 0; q < NCO / 4; ++q) wv[q] = w4[q];
        float iv[4];
        #pragma unroll
        for (int i = 0; i < 4; ++i) iv[i] = sI[(r0 + 4 * i + ky) * RS + xx + kx];
        #pragma unroll
        for (int i = 0; i < 4; ++i) {
          #pragma unroll
          for (int q = 0; q < NCO / 4; ++q) {
            acc[i][4 * q + 0] += iv[i] * wv[q].x;
            acc[i][4 * q + 1] += iv[i] * wv[q].y;
            acc[i][4 * q + 2] += iv[i] * wv[q].z;
            acc[i][4 * q + 3] += iv[i] * wv[q].w;
          }
        }
      }
    }
  }
  __syncthreads();

  if (POOL == 1) {
    #pragma unroll
    for (int j = 0; j < NCO; ++j) {
      int co = coBase + cog * NCO + j;
      float Ar = Ap[co], Cr = Cp[co];
      #pragma unroll
      for (int i = 0; i < 4; ++i) {
        float vO = fmaxf(acc[i][j] * Ar + Cr, 0.f);
        out[((long)img * CO + co) * (HH * WW) + (by + r0 + 4 * i) * WW + bx + xx] = vO;
      }
    }
  } else {
    // fused 2x2 maxpool via cross-lane max
    #pragma unroll
    for (int j = 0; j < NCO; ++j) {
      int co = coBase + cog * NCO + j;
      float Ar = Ap[co], Cr = Cp[co];
      #pragma unroll
      for (int i = 0; i < 4; ++i) {
        float vO = fmaxf(acc[i][j] * Ar + Cr, 0.f);
        float h1 = fmaxf(vO, __shfl_xor(vO, 1));
        float p  = fmaxf(h1, __shfl_xor(h1, 16));
        if ((lane & 17) == 0) {
          int prow = 2 * i + (lane >> 5);
          int pcol = (lane & 15) >> 1;
          if (AVG) {
            smem[(cog * NCO + j) * 65 + prow * 8 + pcol] = p;
          } else {
            out[((long)img * CO + co) * ((HH / 2) * (WW / 2))
                + ((by >> 1) + prow) * (WW / 2) + (bx >> 1) + pcol] = p;
          }
        }
      }
    }
    if (AVG) {
      // global average pool over the 8x8 pooled map -> feats[img][coBase+co]
      __syncthreads();
      int co = tid & 63, q = tid >> 6;
      float s = 0.f;
      #pragma unroll
      for (int p2 = 0; p2 < 16; ++p2) s += smem[co * 65 + q * 16 + p2];
      smem[COT * 65 + q * COT + co] = s;
      __syncthreads();
      if (tid < COT) {
        float s2 = smem[COT * 65 + tid] + smem[COT * 65 + COT + tid]
                 + smem[COT * 65 + 2 * COT + tid] + smem[COT * 65 + 3 * COT + tid];
        out[(long)img * 256 + coBase + tid] = s2 * (1.f / 64.f);
      }
    }
  }
}

// Per-expert heads v2: one block = 64 tokens x 1 expert, 256 threads.
// Gate weights + classifier weights read via wave-uniform (scalar) loads;
// feats staged once in LDS. No spills, all threads busy.
__global__ __launch_bounds__(256) void heads2_kernel(
    const float* __restrict__ feats, const float* __restrict__ gw1,
    const float* __restrict__ gb1, const float* __restrict__ gw2,
    const float* __restrict__ gb2, const float* __restrict__ clsw,
    const float* __restrict__ clsb, const float* __restrict__ usage,
    float* __restrict__ logits_e, float* __restrict__ rs_out)
{
  __shared__ float sF[64 * 257];     // feats tile, stride 257 (2-way-free reads)
  __shared__ float sLg[4 * 64 * 10]; // classifier partials [q][t][c]
  __shared__ float sRed[4 * 64];     // gate partials [wave][t]
  const int tid = threadIdx.x;
  const int b0 = blockIdx.x * 64;
  const int e  = blockIdx.y;

  // stage feats (vectorized)
  for (int idx = tid; idx < 64 * 64; idx += 256) {
    int t = idx >> 6, dg = idx & 63;
    float4 v = ((const float4*)(feats + (long)(b0 + t) * 256))[dg];
    float* p = sF + t * 257 + dg * 4;
    p[0] = v.x; p[1] = v.y; p[2] = v.z; p[3] = v.w;
  }
  __syncthreads();

  const int t  = tid & 63;                                  // token (lane)
  const int hw = __builtin_amdgcn_readfirstlane(tid >> 6);  // wave id (SGPR)

  // ---- classifier partials: wave hw covers d in [hw*64, hw*64+64)
  {
    float acc[10];
    #pragma unroll
    for (int c = 0; c < 10; ++c) acc[c] = 0.f;
    const float* fp = sF + t * 257 + hw * 64;
    const float* cw = clsw + (long)e * 2560 + hw * 64;   // [c][d] rows
    for (int dd = 0; dd < 64; ++dd) {
      float f = fp[dd];
      #pragma unroll
      for (int c = 0; c < 10; ++c) acc[c] += f * cw[c * 256 + dd];
    }
    #pragma unroll
    for (int c = 0; c < 10; ++c) sLg[(hw * 64 + t) * 10 + c] = acc[c];
  }

  // ---- gate: wave hw covers h in [hw*32, hw*32+32)
  {
    float gacc[32];
    #pragma unroll
    for (int j = 0; j < 32; ++j) gacc[j] = 0.f;
    const float* wb = gw1 + ((long)e * 256) * 128 + hw * 32;  // wave-uniform rows
    const float* fp = sF + t * 257;
    for (int d = 0; d < 256; ++d) {
      float f = fp[d];
      const float4* w4 = (const float4*)(wb + (long)d * 128);
      #pragma unroll
      for (int q = 0; q < 8; ++q) {
        float4 w = w4[q];
        gacc[4 * q + 0] += f * w.x; gacc[4 * q + 1] += f * w.y;
        gacc[4 * q + 2] += f * w.z; gacc[4 * q + 3] += f * w.w;
      }
    }
    float s = 0.f;
    const float* b1 = gb1 + e * 128 + hw * 32;
    const float* w2 = gw2 + e * 128 + hw * 32;
    #pragma unroll
    for (int j = 0; j < 32; ++j) s += fmaxf(gacc[j] + b1[j], 0.f) * w2[j];
    sRed[hw * 64 + t] = s;
  }
  __syncthreads();

  // ---- finalize per token (wave 0)
  if (tid < 64) {
    float es = (sRed[t] + sRed[64 + t] + sRed[128 + t] + sRed[192 + t] + gb2[e]) * 0.5f;
    float lg[10];
    #pragma unroll
    for (int c = 0; c < 10; ++c)
      lg[c] = sLg[t * 10 + c] + sLg[(64 + t) * 10 + c]
            + sLg[(128 + t) * 10 + c] + sLg[(192 + t) * 10 + c] + clsb[e * 10 + c];
    float mx = lg[0];
    #pragma unroll
    for (int c = 1; c < 10; ++c) mx = fmaxf(mx, lg[c]);
    float S = 0.f, ps[10];
    #pragma unroll
    for (int c = 0; c < 10; ++c) { ps[c] = expf(lg[c] - mx); S += ps[c]; }
    float inv = 1.f / S, ent = 0.f;
    #pragma unroll
    for (int c = 0; c < 10; ++c) { float p = ps[c] * inv; ent -= p * logf(fmaxf(p, 1e-12f)); }
    float rsv = 0.6f * es + 0.4f * (-ent) - 2.0f * usage[e];
    rs_out[(long)(b0 + t) * 16 + e] = rsv;
    #pragma unroll
    for (int c = 0; c < 10; ++c)
      logits_e[((long)(b0 + t) * 16 + e) * 10 + c] = lg[c];
  }
}

// Per-expert descending argsort of routing scores (ties: lower index first).
__global__ __launch_bounds__(1024) void sort_kernel(
    const float* __restrict__ rs, unsigned* __restrict__ sortedIdx)
{
  __shared__ unsigned long long sk[2048];
  const int e = blockIdx.x;
  const unsigned tid = threadIdx.x;
  for (int i = tid; i < 2048; i += 1024) {
    float f = rs[(long)i * 16 + e];
    unsigned u = __float_as_uint(f);
    u ^= (u >> 31) ? 0xFFFFFFFFu : 0x80000000u;   // monotone map
    sk[i] = ((unsigned long long)(~u) << 32) | (unsigned)i; // asc sort == desc score, asc idx
  }
  for (unsigned k = 2; k <= 2048; k <<= 1) {
    for (unsigned j = k >> 1; j > 0; j >>= 1) {
      __syncthreads();
      unsigned i = ((tid & ~(j - 1)) << 1) | (tid & (j - 1));
      unsigned p = i | j;
      bool asc = ((i & k) == 0);
      unsigned long long a = sk[i], b = sk[p];
      if ((a > b) == asc) { sk[i] = b; sk[p] = a; }
    }
  }
  __syncthreads();
  for (int i = tid; i < 2048; i += 1024)
    sortedIdx[(long)e * 2048 + i] = (unsigned)(sk[i] & 0xFFFFFFFFull);
}

// Sequential capacity-constrained routing + fallback, single block.
__global__ __launch_bounds__(1024) void routing_kernel(
    const unsigned* __restrict__ sortedIdx, const float* __restrict__ rs,
    float* __restrict__ Dout, unsigned* __restrict__ dmaskOut)
{
  __shared__ unsigned char sAvail[2048];
  __shared__ unsigned sDm[2048];
  __shared__ int sLoads[16];
  __shared__ int sWaveCnt[16];
  __shared__ int sNtc, sVC;
  const int tid = threadIdx.x;
  const int lane = tid & 63, wave = tid >> 6;
  for (int i = tid; i < 2048; i += 1024) { sAvail[i] = 1; sDm[i] = 0; }
  if (tid < 16) sLoads[tid] = 0;
  if (tid == 0) sVC = 2048;
  __syncthreads();
  for (int it = 0; it < 3; ++it) {
    for (int j = 0; j < 16; ++j) {
      if (tid == 0) {
        int rc = 256 - sLoads[j]; if (rc < 0) rc = 0;
        int vc = sVC, ntc = 0;
        if (rc > 0 && vc > 0) {
          int a = rc < vc ? rc : vc;
          int b2 = vc < 102 ? vc : 102;
          ntc = a > b2 ? a : b2;
        }
        sNtc = ntc; sLoads[j] += ntc; sVC -= ntc;
      }
      __syncthreads();
      const int ntc = sNtc;
      if (ntc > 0) {
        int base = 0;
        for (int p = 0; p < 2; ++p) {
          int i = p * 1024 + tid;
          unsigned tok = sortedIdx[(long)j * 2048 + i];
          int fl = sAvail[tok] ? 1 : 0;
          unsigned long long bm = __ballot(fl);
          if (lane == 0) sWaveCnt[wave] = __popcll(bm);
          __syncthreads();
          int off = base;
          for (int w = 0; w < wave; ++w) off += sWaveCnt[w];
          int pre = off + __popcll(bm & ((1ull << lane) - 1ull));
          if (fl && pre < ntc) { sAvail[tok] = 0; sDm[tok] |= (1u << j); }
          int tot = base;
          for (int w = 0; w < 16; ++w) tot += sWaveCnt[w];
          base = tot;
          __syncthreads();
        }
      }
      __syncthreads();
    }
  }
  // fallback: least-loaded of per-token top-3 (sequential, usually 0 tokens)
  if (tid == 0 && sVC > 0) {
    for (int i = 0; i < 2048; ++i) {
      if (!sAvail[i]) continue;
      float s0 = -3.4e38f, s1 = s0, s2 = s0; int e0 = 0, e1 = 0, e2 = 0;
      for (int e = 0; e < 16; ++e) {
        float s = rs[i * 16 + e];
        if (s > s0)      { s2 = s1; e2 = e1; s1 = s0; e1 = e0; s0 = s; e0 = e; }
        else if (s > s1) { s2 = s1; e2 = e1; s1 = s;  e1 = e; }
        else if (s > s2) { s2 = s;  e2 = e; }
      }
      int best = e0, bl = sLoads[e0];
      if (sLoads[e1] < bl) { best = e1; bl = sLoads[e1]; }
      if (sLoads[e2] < bl) { best = e2; bl = sLoads[e2]; }
      sDm[i] |= (1u << best);
      sLoads[best] += 1;
    }
  }
  __syncthreads();
  for (int idx = tid; idx < 2048 * 16; idx += 1024) {
    int tok = idx >> 4, e = idx & 15;
    Dout[idx] = ((sDm[tok] >> e) & 1u) ? 1.0f : 0.0f;
  }
  for (int i = tid; i < 2048; i += 1024) dmaskOut[i] = sDm[i];
}

__global__ __launch_bounds__(256) void combine_kernel(
    const unsigned* __restrict__ dmask, const float* __restrict__ rs,
    const float* __restrict__ L, float* __restrict__ out)
{
  int i = blockIdx.x * 256 + threadIdx.x;
  if (i >= 2048) return;
  unsigned dm = dmask[i];
  float r[16];
  #pragma unroll
  for (int e = 0; e < 16; ++e) r[e] = rs[i * 16 + e];
  float mx = -3.4e38f;
  #pragma unroll
  for (int e = 0; e < 16; ++e) {
    float v = ((dm >> e) & 1u) ? r[e] : 0.0f;   // matches active = rs * D, max incl. zeros
    mx = fmaxf(mx, v);
  }
  float w[16], S = 0.f;
  #pragma unroll
  for (int e = 0; e < 16; ++e) {
    w[e] = ((dm >> e) & 1u) ? expf(r[e] - mx) : 0.0f;
    S += w[e];
  }
  float inv = 1.f / S;
  #pragma unroll
  for (int c = 0; c < 10; ++c) {
    float a = 0.f;
    #pragma unroll
    for (int e = 0; e < 16; ++e) a += w[e] * L[((long)i * 16 + e) * 10 + c];
    out[i * 10 + c] = a * inv;
  }
}

extern "C" void kernel_launch(void* const* d_in, const int* in_sizes, int n_in,
                              void* d_out, int out_size, void* d_ws, size_t ws_size,
                              hipStream_t stream)
{
  const float* x    = (const float*)d_in[0];
  const float* cw1  = (const float*)d_in[1];
  const float* cb1  = (const float*)d_in[2];
  const float* g1   = (const float*)d_in[3];
  const float* be1  = (const float*)d_in[4];
  const float* m1   = (const float*)d_in[5];
  const float* v1   = (const float*)d_in[6];
  const float* cw2  = (const float*)d_in[7];
  const float* cb2  = (const float*)d_in[8];
  const float* g2   = (const float*)d_in[9];
  const float* be2  = (const float*)d_in[10];
  const float* m2   = (const float*)d_in[11];
  const float* v2   = (const float*)d_in[12];
  const float* cw3  = (const float*)d_in[13];
  const float* cb3  = (const float*)d_in[14];
  const float* g3   = (const float*)d_in[15];
  const float* be3  = (const float*)d_in[16];
  const float* m3   = (const float*)d_in[17];
  const float* v3   = (const float*)d_in[18];
  const float* cw4  = (const float*)d_in[19];
  const float* cb4  = (const float*)d_in[20];
  const float* g4   = (const float*)d_in[21];
  const float* be4  = (const float*)d_in[22];
  const float* m4   = (const float*)d_in[23];
  const float* v4   = (const float*)d_in[24];
  const float* gw1  = (const float*)d_in[25];
  const float* gb1  = (const float*)d_in[26];
  const float* gw2  = (const float*)d_in[27];
  const float* gb2  = (const float*)d_in[28];
  const float* clsw = (const float*)d_in[29];
  const float* clsb = (const float*)d_in[30];
  const float* usage = (const float*)d_in[31];

  float* out = (float*)d_out;
  float* ws  = (float*)d_ws;

  // workspace layout (floats)
  float* A1 = ws + 0;   float* C1 = ws + 32;
  float* A2 = ws + 64;  float* C2 = ws + 128;
  float* A3 = ws + 192; float* C3 = ws + 320;
  float* A4 = ws + 448; float* C4 = ws + 704;
  float* feats   = ws + 1024;                       // 2048*256
  float* logitsE = ws + 1024 + 524288;              // 2048*16*10
  unsigned* sortedIdx = (unsigned*)(ws + 852992);   // 16*2048
  unsigned* dmask     = (unsigned*)(ws + 885760);   // 2048
  float* bufBase = ws + 887808;

  long wsFloats = (long)(ws_size / 4);
  long availF = wsFloats - 887808;
  long chunkL = availF / 49152;                     // 32768 (bufA) + 16384 (bufB) per image
  int chunk = (int)(chunkL < 1 ? 1 : (chunkL > 2048 ? 2048 : chunkL));

  bnprep_kernel<<<1, 256, 0, stream>>>(g1, be1, m1, v1, cb1, A1, C1, 32);
  bnprep_kernel<<<1, 256, 0, stream>>>(g2, be2, m2, v2, cb2, A2, C2, 64);
  bnprep_kernel<<<1, 256, 0, stream>>>(g3, be3, m3, v3, cb3, A3, C3, 128);
  bnprep_kernel<<<1, 256, 0, stream>>>(g4, be4, m4, v4, cb4, A4, C4, 256);

  float* bufA = bufBase;
  float* bufB = bufBase + (long)chunk * 32768;

  for (int ib = 0; ib < 2048; ib += chunk) {
    int n = 2048 - ib; if (n > chunk) n = chunk;
    conv3x3_kernel<3, 32, 32, 32, 32, 1, 3, 0>
        <<<dim3(n, 4), 256, 0, stream>>>(x + (long)ib * 3072, cw1, A1, C1, bufA);
    conv3x3_kernel<32, 64, 64, 32, 32, 2, 16, 0>
        <<<dim3(n, 4), 256, 0, stream>>>(bufA, cw2, A2, C2, bufB);
    conv3x3_kernel<64, 128, 64, 16, 16, 1, 16, 0>
        <<<dim3(n * 2, 1), 256, 0, stream>>>(bufB, cw3, A3, C3, bufA);
    conv3x3_kernel<128, 256, 64, 16, 16, 2, 16, 1>
        <<<dim3(n * 4, 1), 256, 0, stream>>>(bufA, cw4, A4, C4, feats + (long)ib * 256);
  }

  float* rsOut = out + 20480;   // routing_scores region [2048,16]
  heads2_kernel<<<dim3(32, 16), 256, 0, stream>>>(feats, gw1, gb1, gw2, gb2,
                                                  clsw, clsb, usage, logitsE, rsOut);
  sort_kernel<<<16, 1024, 0, stream>>>(rsOut, sortedIdx);
  routing_kernel<<<1, 1024, 0, stream>>>(sortedIdx, rsOut, out + 53248, dmask);
  combine_kernel<<<8, 256, 0, stream>>>(dmask, rsOut, logitsE, out);
}

// Round 3
// 3381.947 us; speedup vs baseline: 2.7870x; 2.1714x over previous
//
#include <hip/hip_runtime.h>

typedef __attribute__((ext_vector_type(8))) short short8;
typedef __attribute__((ext_vector_type(4))) float f32x4;

__device__ __forceinline__ unsigned short f2bf(float f) {
  unsigned u = __float_as_uint(f);
  unsigned r = (u + 0x7fffu + ((u >> 16) & 1u)) >> 16;
  return (unsigned short)r;
}
__device__ __forceinline__ float bf2f(unsigned short h) {
  return __uint_as_float(((unsigned)h) << 16);
}

// ---------------------------------------------------------------------------
__global__ __launch_bounds__(256) void bnprep_kernel(
    const float* __restrict__ g, const float* __restrict__ be,
    const float* __restrict__ m, const float* __restrict__ v,
    const float* __restrict__ b, float* __restrict__ A, float* __restrict__ C, int n)
{
  int i = blockIdx.x * 256 + threadIdx.x;
  if (i < n) {
    float s = g[i] / sqrtf(v[i] + 1e-5f);
    A[i] = s;
    C[i] = (b[i] - m[i]) * s + be[i];
  }
}

// Split fp32 weights into hi/lo bf16, layout [shift][co][hi CI | lo CI] halves.
__global__ __launch_bounds__(256) void wprep_kernel(
    const float* __restrict__ w, unsigned short* __restrict__ wT, int CO, int CI)
{
  int idx = blockIdx.x * 256 + threadIdx.x;
  int total = CO * CI * 9;
  if (idx >= total) return;
  int k = idx % 9;
  int ci = (idx / 9) % CI;
  int co = idx / (9 * CI);
  float f = w[idx];
  unsigned short h = f2bf(f);
  unsigned short l = f2bf(f - bf2f(h));
  long base = ((long)(k * CO + co)) * (2 * CI) + ci;
  wT[base] = h;
  wT[base + CI] = l;
}

// conv1: 3->32, 32x32, fp32 compute, emits channel-last split-bf16.
__global__ __launch_bounds__(256) void conv1_kernel(
    const float* __restrict__ in, const float* __restrict__ wgt,
    const float* __restrict__ Ap, const float* __restrict__ Cp,
    unsigned short* __restrict__ out)
{
  __shared__ alignas(16) float smem[3 * 432 + 864];
  const int tid = threadIdx.x;
  const int img = blockIdx.x;
  const int by = (blockIdx.y >> 1) * 16, bx = (blockIdx.y & 1) * 16;
  const int r0 = (tid & 63) >> 4, xx = tid & 15, cog = tid >> 6;

  float acc[4][8];
  #pragma unroll
  for (int i = 0; i < 4; ++i)
    #pragma unroll
    for (int j = 0; j < 8; ++j) acc[i][j] = 0.f;

  for (int e = tid; e < 972; e += 256) {
    int ci = e / 324, rem = e - ci * 324;
    int rr = rem / 18, cc = rem - rr * 18;
    int gy = by + rr - 1, gx = bx + cc - 1;
    float v = 0.f;
    if (gy >= 0 && gy < 32 && gx >= 0 && gx < 32)
      v = in[(long)img * 3072 + ci * 1024 + gy * 32 + gx];
    smem[ci * 432 + rr * 24 + cc] = v;
  }
  for (int e = tid; e < 864; e += 256) {
    int co = e & 31, rem = e >> 5;  // rem = ci*9+k
    smem[1296 + rem * 32 + co] = wgt[(long)co * 27 + rem];
  }
  __syncthreads();
  for (int ci = 0; ci < 3; ++ci) {
    #pragma unroll
    for (int k = 0; k < 9; ++k) {
      int ky = k / 3, kx = k - 3 * (k / 3);
      const float4* w4 = (const float4*)(smem + 1296 + (ci * 9 + k) * 32 + cog * 8);
      float4 w0 = w4[0], w1 = w4[1];
      #pragma unroll
      for (int i = 0; i < 4; ++i) {
        float iv = smem[ci * 432 + (r0 + 4 * i + ky) * 24 + xx + kx];
        acc[i][0] += iv * w0.x; acc[i][1] += iv * w0.y;
        acc[i][2] += iv * w0.z; acc[i][3] += iv * w0.w;
        acc[i][4] += iv * w1.x; acc[i][5] += iv * w1.y;
        acc[i][6] += iv * w1.z; acc[i][7] += iv * w1.w;
      }
    }
  }
  #pragma unroll
  for (int j = 0; j < 8; ++j) {
    int co = cog * 8 + j;
    float Ar = Ap[co], Cr = Cp[co];
    #pragma unroll
    for (int i = 0; i < 4; ++i) {
      float vv = fmaxf(acc[i][j] * Ar + Cr, 0.f);
      unsigned short h = f2bf(vv);
      unsigned short l = f2bf(vv - bf2f(h));
      long px = (long)img * 1024 + (by + r0 + 4 * i) * 32 + bx + xx;
      out[px * 64 + co] = h;
      out[px * 64 + 32 + co] = l;
    }
  }
}

// ---------------------------------------------------------------------------
// Split-bf16 MFMA conv: 9 shifted GEMMs, K=ci (chunks of 32).
// Block: 256 output px (16x16 tile) x 64 co, 4 waves (wave: 64 px x 64 co).
// A tile: [324 px][hi32|lo32|pad8] halves; B: [9][64 co][hi32|lo32|pad8].
// MODE 0: plain store; 1: 2x2 maxpool store; 2: pool + global-avg -> feats.
template<int H, int CI, int CO, int MODE>
__global__ __launch_bounds__(256) void convmf_kernel(
    const unsigned short* __restrict__ actIn, const unsigned short* __restrict__ wT,
    const float* __restrict__ Ap, const float* __restrict__ Cp,
    void* __restrict__ outP)
{
  constexpr int NCB = CI / 32;
  constexpr int TILES = (H == 32) ? 4 : 1;
  constexpr int COG = CO / 64;
  constexpr int TPI = TILES * COG;
  constexpr int PIX_IN = 2 * CI;
  constexpr int BOFF = 23328;          // halves: A = 324*72
  __shared__ alignas(16) unsigned short smem[64800];   // 129.6 KB

  const int tid = threadIdx.x;
  const int bx = blockIdx.x;
  const int img = bx / TPI;
  const int sub = bx % TPI;
  const int tY0 = (H == 32) ? ((sub >> 1) & 1) * 16 : 0;
  const int tX0 = (H == 32) ? (sub & 1) * 16 : 0;
  const int coG = (H == 32) ? 0 : sub;

  const int lx = tid & 15;
  const int g  = (tid & 63) >> 4;
  const int w  = tid >> 6;

  f32x4 acc[4][4];
  #pragma unroll
  for (int i = 0; i < 4; ++i)
    #pragma unroll
    for (int j = 0; j < 4; ++j) acc[i][j] = (f32x4){0.f, 0.f, 0.f, 0.f};

  for (int cb = 0; cb < NCB; ++cb) {
    if (cb) __syncthreads();
    // ---- stage A tile (halo, zero-padded): 324 px x 8 chunks of 16B
    float4 av[11];
    #pragma unroll
    for (int i = 0; i < 11; ++i) {
      int idx = tid + i * 256;
      if (idx < 2592) {
        int lp = idx >> 3, c = idx & 7;
        int ry = lp / 18, rx = lp - ry * 18;
        int gy = tY0 + ry - 1, gx = tX0 + rx - 1;
        int coff = (c < 4) ? (cb * 32 + c * 8) : (CI + cb * 32 + (c - 4) * 8);
        if (gy >= 0 && gy < H && gx >= 0 && gx < H) {
          av[i] = *(const float4*)(actIn + ((long)img * H * H + gy * H + gx) * PIX_IN + coff);
        } else {
          av[i] = (float4){0.f, 0.f, 0.f, 0.f};
        }
      }
    }
    // ---- stage B: 9 shifts x 64 co x 8 chunks
    float4 bv[18];
    #pragma unroll
    for (int i = 0; i < 18; ++i) {
      int idx = tid + i * 256;
      int c = idx & 7, co = (idx >> 3) & 63, s = idx >> 9;
      int coff = (c < 4) ? (cb * 32 + c * 8) : (CI + cb * 32 + (c - 4) * 8);
      bv[i] = *(const float4*)(wT + ((long)(s * CO + coG * 64 + co)) * PIX_IN + coff);
    }
    #pragma unroll
    for (int i = 0; i < 11; ++i) {
      int idx = tid + i * 256;
      if (idx < 2592) {
        int lp = idx >> 3, c = idx & 7;
        *(float4*)(smem + lp * 72 + c * 8) = av[i];
      }
    }
    #pragma unroll
    for (int i = 0; i < 18; ++i) {
      int idx = tid + i * 256;
      int c = idx & 7, co = (idx >> 3) & 63, s = idx >> 9;
      *(float4*)(smem + BOFF + (s * 64 + co) * 72 + c * 8) = bv[i];
    }
    __syncthreads();

    // ---- 9 shifted GEMM steps, all LDS-resident
    for (int s = 0; s < 9; ++s) {
      int ky = s / 3, kx = s - 3 * (s / 3);
      short8 bh[4], bl[4];
      #pragma unroll
      for (int nf = 0; nf < 4; ++nf) {
        const unsigned short* bp = smem + BOFF + (s * 64 + nf * 16 + lx) * 72 + g * 8;
        bh[nf] = *(const short8*)bp;
        bl[nf] = *(const short8*)(bp + 32);
      }
      #pragma unroll
      for (int mf = 0; mf < 4; ++mf) {
        int y = w * 4 + mf;
        const unsigned short* ap = smem + ((y + ky) * 18 + lx + kx) * 72 + g * 8;
        short8 ah = *(const short8*)ap;
        short8 al = *(const short8*)(ap + 32);
        #pragma unroll
        for (int nf = 0; nf < 4; ++nf)
          acc[mf][nf] = __builtin_amdgcn_mfma_f32_16x16x32_bf16(ah, bh[nf], acc[mf][nf], 0, 0, 0);
        #pragma unroll
        for (int nf = 0; nf < 4; ++nf)
          acc[mf][nf] = __builtin_amdgcn_mfma_f32_16x16x32_bf16(ah, bl[nf], acc[mf][nf], 0, 0, 0);
        #pragma unroll
        for (int nf = 0; nf < 4; ++nf)
          acc[mf][nf] = __builtin_amdgcn_mfma_f32_16x16x32_bf16(al, bh[nf], acc[mf][nf], 0, 0, 0);
      }
    }
  }

  // ---- epilogue. D frag: M-row (=x within frag row y) = 4*g + reg, N-col = lx.
  if (MODE == 0) {
    unsigned short* outA = (unsigned short*)outP;
    #pragma unroll
    for (int nf = 0; nf < 4; ++nf) {
      int co = coG * 64 + nf * 16 + lx;
      float Ar = Ap[co], Cr = Cp[co];
      #pragma unroll
      for (int mf = 0; mf < 4; ++mf) {
        int y = w * 4 + mf;
        #pragma unroll
        for (int r = 0; r < 4; ++r) {
          int x = 4 * g + r;
          float vv = fmaxf(acc[mf][nf][r] * Ar + Cr, 0.f);
          unsigned short h = f2bf(vv);
          unsigned short l = f2bf(vv - bf2f(h));
          long px = (long)img * 256 + y * 16 + x;
          outA[px * (2 * CO) + co] = h;
          outA[px * (2 * CO) + CO + co] = l;
        }
      }
    }
  } else if (MODE == 1) {
    unsigned short* outA = (unsigned short*)outP;
    #pragma unroll
    for (int nf = 0; nf < 4; ++nf) {
      int co = nf * 16 + lx;
      float Ar = Ap[co], Cr = Cp[co];
      #pragma unroll
      for (int mfp = 0; mfp < 2; ++mfp) {
        int oy = tY0 / 2 + w * 2 + mfp;
        #pragma unroll
        for (int rp = 0; rp < 2; ++rp) {
          int ox = tX0 / 2 + 2 * g + rp;
          float v = fmaxf(fmaxf(acc[2 * mfp][nf][2 * rp], acc[2 * mfp][nf][2 * rp + 1]),
                          fmaxf(acc[2 * mfp + 1][nf][2 * rp], acc[2 * mfp + 1][nf][2 * rp + 1]));
          float vv = fmaxf(v * Ar + Cr, 0.f);
          unsigned short h = f2bf(vv);
          unsigned short l = f2bf(vv - bf2f(h));
          long px = (long)img * 256 + oy * 16 + ox;
          outA[px * 128 + co] = h;
          outA[px * 128 + 64 + co] = l;
        }
      }
    }
  } else {
    // pool + BN/ReLU + global average -> feats[img][coG*64 + co] (fp32)
    float psum[4] = {0.f, 0.f, 0.f, 0.f};
    #pragma unroll
    for (int nf = 0; nf < 4; ++nf) {
      int co = coG * 64 + nf * 16 + lx;
      float Ar = Ap[co], Cr = Cp[co];
      #pragma unroll
      for (int mfp = 0; mfp < 2; ++mfp) {
        #pragma unroll
        for (int rp = 0; rp < 2; ++rp) {
          float v = fmaxf(fmaxf(acc[2 * mfp][nf][2 * rp], acc[2 * mfp][nf][2 * rp + 1]),
                          fmaxf(acc[2 * mfp + 1][nf][2 * rp], acc[2 * mfp + 1][nf][2 * rp + 1]));
          psum[nf] += fmaxf(v * Ar + Cr, 0.f);
        }
      }
    }
    #pragma unroll
    for (int nf = 0; nf < 4; ++nf) {
      psum[nf] += __shfl_xor(psum[nf], 16);
      psum[nf] += __shfl_xor(psum[nf], 32);
    }
    __syncthreads();
    float* sR = (float*)smem;
    if (((tid & 63) >> 4) == 0) {
      #pragma unroll
      for (int nf = 0; nf < 4; ++nf) sR[w * 64 + nf * 16 + lx] = psum[nf];
    }
    __syncthreads();
    if (tid < 64) {
      float s = sR[tid] + sR[64 + tid] + sR[128 + tid] + sR[192 + tid];
      ((float*)outP)[(long)img * 256 + coG * 64 + tid] = s * (1.f / 64.f);
    }
  }
}

// ---------------------------------------------------------------------------
// heads / sort / routing / combine (unchanged from round 2)
__global__ __launch_bounds__(256) void heads2_kernel(
    const float* __restrict__ feats, const float* __restrict__ gw1,
    const float* __restrict__ gb1, const float* __restrict__ gw2,
    const float* __restrict__ gb2, const float* __restrict__ clsw,
    const float* __restrict__ clsb, const float* __restrict__ usage,
    float* __restrict__ logits_e, float* __restrict__ rs_out)
{
  __shared__ float sF[64 * 257];
  __shared__ float sLg[4 * 64 * 10];
  __shared__ float sRed[4 * 64];
  const int tid = threadIdx.x;
  const int b0 = blockIdx.x * 64;
  const int e  = blockIdx.y;

  for (int idx = tid; idx < 64 * 64; idx += 256) {
    int t = idx >> 6, dg = idx & 63;
    float4 v = ((const float4*)(feats + (long)(b0 + t) * 256))[dg];
    float* p = sF + t * 257 + dg * 4;
    p[0] = v.x; p[1] = v.y; p[2] = v.z; p[3] = v.w;
  }
  __syncthreads();

  const int t  = tid & 63;
  const int hw = __builtin_amdgcn_readfirstlane(tid >> 6);

  {
    float acc[10];
    #pragma unroll
    for (int c = 0; c < 10; ++c) acc[c] = 0.f;
    const float* fp = sF + t * 257 + hw * 64;
    const float* cw = clsw + (long)e * 2560 + hw * 64;
    for (int dd = 0; dd < 64; ++dd) {
      float f = fp[dd];
      #pragma unroll
      for (int c = 0; c < 10; ++c) acc[c] += f * cw[c * 256 + dd];
    }
    #pragma unroll
    for (int c = 0; c < 10; ++c) sLg[(hw * 64 + t) * 10 + c] = acc[c];
  }
  {
    float gacc[32];
    #pragma unroll
    for (int j = 0; j < 32; ++j) gacc[j] = 0.f;
    const float* wb = gw1 + ((long)e * 256) * 128 + hw * 32;
    const float* fp = sF + t * 257;
    for (int d = 0; d < 256; ++d) {
      float f = fp[d];
      const float4* w4 = (const float4*)(wb + (long)d * 128);
      #pragma unroll
      for (int q = 0; q < 8; ++q) {
        float4 wv = w4[q];
        gacc[4 * q + 0] += f * wv.x; gacc[4 * q + 1] += f * wv.y;
        gacc[4 * q + 2] += f * wv.z; gacc[4 * q + 3] += f * wv.w;
      }
    }
    float s = 0.f;
    const float* b1 = gb1 + e * 128 + hw * 32;
    const float* w2 = gw2 + e * 128 + hw * 32;
    #pragma unroll
    for (int j = 0; j < 32; ++j) s += fmaxf(gacc[j] + b1[j], 0.f) * w2[j];
    sRed[hw * 64 + t] = s;
  }
  __syncthreads();

  if (tid < 64) {
    float es = (sRed[t] + sRed[64 + t] + sRed[128 + t] + sRed[192 + t] + gb2[e]) * 0.5f;
    float lg[10];
    #pragma unroll
    for (int c = 0; c < 10; ++c)
      lg[c] = sLg[t * 10 + c] + sLg[(64 + t) * 10 + c]
            + sLg[(128 + t) * 10 + c] + sLg[(192 + t) * 10 + c] + clsb[e * 10 + c];
    float mx = lg[0];
    #pragma unroll
    for (int c = 1; c < 10; ++c) mx = fmaxf(mx, lg[c]);
    float S = 0.f, ps[10];
    #pragma unroll
    for (int c = 0; c < 10; ++c) { ps[c] = expf(lg[c] - mx); S += ps[c]; }
    float inv = 1.f / S, ent = 0.f;
    #pragma unroll
    for (int c = 0; c < 10; ++c) { float p = ps[c] * inv; ent -= p * logf(fmaxf(p, 1e-12f)); }
    float rsv = 0.6f * es + 0.4f * (-ent) - 2.0f * usage[e];
    rs_out[(long)(b0 + t) * 16 + e] = rsv;
    #pragma unroll
    for (int c = 0; c < 10; ++c)
      logits_e[((long)(b0 + t) * 16 + e) * 10 + c] = lg[c];
  }
}

__global__ __launch_bounds__(1024) void sort_kernel(
    const float* __restrict__ rs, unsigned* __restrict__ sortedIdx)
{
  __shared__ unsigned long long sk[2048];
  const int e = blockIdx.x;
  const unsigned tid = threadIdx.x;
  for (int i = tid; i < 2048; i += 1024) {
    float f = rs[(long)i * 16 + e];
    unsigned u = __float_as_uint(f);
    u ^= (u >> 31) ? 0xFFFFFFFFu : 0x80000000u;
    sk[i] = ((unsigned long long)(~u) << 32) | (unsigned)i;
  }
  for (unsigned k = 2; k <= 2048; k <<= 1) {
    for (unsigned j = k >> 1; j > 0; j >>= 1) {
      __syncthreads();
      unsigned i = ((tid & ~(j - 1)) << 1) | (tid & (j - 1));
      unsigned p = i | j;
      bool asc = ((i & k) == 0);
      unsigned long long a = sk[i], b = sk[p];
      if ((a > b) == asc) { sk[i] = b; sk[p] = a; }
    }
  }
  __syncthreads();
  for (int i = tid; i < 2048; i += 1024)
    sortedIdx[(long)e * 2048 + i] = (unsigned)(sk[i] & 0xFFFFFFFFull);
}

__global__ __launch_bounds__(1024) void routing_kernel(
    const unsigned* __restrict__ sortedIdx, const float* __restrict__ rs,
    float* __restrict__ Dout, unsigned* __restrict__ dmaskOut)
{
  __shared__ unsigned char sAvail[2048];
  __shared__ unsigned sDm[2048];
  __shared__ int sLoads[16];
  __shared__ int sWaveCnt[16];
  __shared__ int sNtc, sVC;
  const int tid = threadIdx.x;
  const int lane = tid & 63, wave = tid >> 6;
  for (int i = tid; i < 2048; i += 1024) { sAvail[i] = 1; sDm[i] = 0; }
  if (tid < 16) sLoads[tid] = 0;
  if (tid == 0) sVC = 2048;
  __syncthreads();
  for (int it = 0; it < 3; ++it) {
    for (int j = 0; j < 16; ++j) {
      if (tid == 0) {
        int rc = 256 - sLoads[j]; if (rc < 0) rc = 0;
        int vc = sVC, ntc = 0;
        if (rc > 0 && vc > 0) {
          int a = rc < vc ? rc : vc;
          int b2 = vc < 102 ? vc : 102;
          ntc = a > b2 ? a : b2;
        }
        sNtc = ntc; sLoads[j] += ntc; sVC -= ntc;
      }
      __syncthreads();
      const int ntc = sNtc;
      if (ntc > 0) {
        int base = 0;
        for (int p = 0; p < 2; ++p) {
          int i = p * 1024 + tid;
          unsigned tok = sortedIdx[(long)j * 2048 + i];
          int fl = sAvail[tok] ? 1 : 0;
          unsigned long long bm = __ballot(fl);
          if (lane == 0) sWaveCnt[wave] = __popcll(bm);
          __syncthreads();
          int off = base;
          for (int w = 0; w < wave; ++w) off += sWaveCnt[w];
          int pre = off + __popcll(bm & ((1ull << lane) - 1ull));
          if (fl && pre < ntc) { sAvail[tok] = 0; sDm[tok] |= (1u << j); }
          int tot = base;
          for (int w = 0; w < 16; ++w) tot += sWaveCnt[w];
          base = tot;
          __syncthreads();
        }
      }
      __syncthreads();
    }
  }
  if (tid == 0 && sVC > 0) {
    for (int i = 0; i < 2048; ++i) {
      if (!sAvail[i]) continue;
      float s0 = -3.4e38f, s1 = s0, s2 = s0; int e0 = 0, e1 = 0, e2 = 0;
      for (int e = 0; e < 16; ++e) {
        float s = rs[i * 16 + e];
        if (s > s0)      { s2 = s1; e2 = e1; s1 = s0; e1 = e0; s0 = s; e0 = e; }
        else if (s > s1) { s2 = s1; e2 = e1; s1 = s;  e1 = e; }
        else if (s > s2) { s2 = s;  e2 = e; }
      }
      int best = e0, bl = sLoads[e0];
      if (sLoads[e1] < bl) { best = e1; bl = sLoads[e1]; }
      if (sLoads[e2] < bl) { best = e2; bl = sLoads[e2]; }
      sDm[i] |= (1u << best);
      sLoads[best] += 1;
    }
  }
  __syncthreads();
  for (int idx = tid; idx < 2048 * 16; idx += 1024) {
    int tok = idx >> 4, e = idx & 15;
    Dout[idx] = ((sDm[tok] >> e) & 1u) ? 1.0f : 0.0f;
  }
  for (int i = tid; i < 2048; i += 1024) dmaskOut[i] = sDm[i];
}

__global__ __launch_bounds__(256) void combine_kernel(
    const unsigned* __restrict__ dmask, const float* __restrict__ rs,
    const float* __restrict__ L, float* __restrict__ out)
{
  int i = blockIdx.x * 256 + threadIdx.x;
  if (i >= 2048) return;
  unsigned dm = dmask[i];
  float r[16];
  #pragma unroll
  for (int e = 0; e < 16; ++e) r[e] = rs[i * 16 + e];
  float mx = -3.4e38f;
  #pragma unroll
  for (int e = 0; e < 16; ++e) {
    float v = ((dm >> e) & 1u) ? r[e] : 0.0f;
    mx = fmaxf(mx, v);
  }
  float w[16], S = 0.f;
  #pragma unroll
  for (int e = 0; e < 16; ++e) {
    w[e] = ((dm >> e) & 1u) ? expf(r[e] - mx) : 0.0f;
    S += w[e];
  }
  float inv = 1.f / S;
  #pragma unroll
  for (int c = 0; c < 10; ++c) {
    float a = 0.f;
    #pragma unroll
    for (int e = 0; e < 16; ++e) a += w[e] * L[((long)i * 16 + e) * 10 + c];
    out[i * 10 + c] = a * inv;
  }
}

// ---------------------------------------------------------------------------
extern "C" void kernel_launch(void* const* d_in, const int* in_sizes, int n_in,
                              void* d_out, int out_size, void* d_ws, size_t ws_size,
                              hipStream_t stream)
{
  const float* x    = (const float*)d_in[0];
  const float* cw1  = (const float*)d_in[1];
  const float* cb1  = (const float*)d_in[2];
  const float* g1   = (const float*)d_in[3];
  const float* be1  = (const float*)d_in[4];
  const float* m1   = (const float*)d_in[5];
  const float* v1   = (const float*)d_in[6];
  const float* cw2  = (const float*)d_in[7];
  const float* cb2  = (const float*)d_in[8];
  const float* g2   = (const float*)d_in[9];
  const float* be2  = (const float*)d_in[10];
  const float* m2   = (const float*)d_in[11];
  const float* v2   = (const float*)d_in[12];
  const float* cw3  = (const float*)d_in[13];
  const float* cb3  = (const float*)d_in[14];
  const float* g3   = (const float*)d_in[15];
  const float* be3  = (const float*)d_in[16];
  const float* m3   = (const float*)d_in[17];
  const float* v3   = (const float*)d_in[18];
  const float* cw4  = (const float*)d_in[19];
  const float* cb4  = (const float*)d_in[20];
  const float* g4   = (const float*)d_in[21];
  const float* be4  = (const float*)d_in[22];
  const float* m4   = (const float*)d_in[23];
  const float* v4   = (const float*)d_in[24];
  const float* gw1  = (const float*)d_in[25];
  const float* gb1  = (const float*)d_in[26];
  const float* gw2  = (const float*)d_in[27];
  const float* gb2  = (const float*)d_in[28];
  const float* clsw = (const float*)d_in[29];
  const float* clsb = (const float*)d_in[30];
  const float* usage = (const float*)d_in[31];

  float* out = (float*)d_out;
  float* ws  = (float*)d_ws;

  float* A1 = ws + 0;   float* C1 = ws + 32;
  float* A2 = ws + 64;  float* C2 = ws + 128;
  float* A3 = ws + 192; float* C3 = ws + 320;
  float* A4 = ws + 448; float* C4 = ws + 704;
  float* feats   = ws + 1024;                       // 2048*256
  float* logitsE = ws + 525312;                     // 2048*16*10
  unsigned* sortedIdx = (unsigned*)(ws + 852992);   // 16*2048
  unsigned* dmask     = (unsigned*)(ws + 885760);   // 2048
  unsigned short* wT2 = (unsigned short*)(ws + 887808);   // 36864 halves
  unsigned short* wT3 = (unsigned short*)(ws + 906240);   // 147456 halves
  unsigned short* wT4 = (unsigned short*)(ws + 979968);   // 589824 halves
  const long bufBase = 1274880;

  long wsFloats = (long)(ws_size / 4);
  long availF = wsFloats - bufBase;
  long chunkL = availF / 49152;   // per-img: act1/act3 32768 f + act2 16384 f
  int chunk = (int)(chunkL < 1 ? 1 : (chunkL > 2048 ? 2048 : chunkL));

  bnprep_kernel<<<1, 256, 0, stream>>>(g1, be1, m1, v1, cb1, A1, C1, 32);
  bnprep_kernel<<<1, 256, 0, stream>>>(g2, be2, m2, v2, cb2, A2, C2, 64);
  bnprep_kernel<<<1, 256, 0, stream>>>(g3, be3, m3, v3, cb3, A3, C3, 128);
  bnprep_kernel<<<1, 256, 0, stream>>>(g4, be4, m4, v4, cb4, A4, C4, 256);
  wprep_kernel<<<(64 * 32 * 9 + 255) / 256, 256, 0, stream>>>(cw2, wT2, 64, 32);
  wprep_kernel<<<(128 * 64 * 9 + 255) / 256, 256, 0, stream>>>(cw3, wT3, 128, 64);
  wprep_kernel<<<(256 * 128 * 9 + 255) / 256, 256, 0, stream>>>(cw4, wT4, 256, 128);

  unsigned short* bufA = (unsigned short*)(ws + bufBase);
  unsigned short* bufB = bufA + (long)chunk * 65536;

  for (int ib = 0; ib < 2048; ib += chunk) {
    int n = 2048 - ib; if (n > chunk) n = chunk;
    conv1_kernel<<<dim3(n, 4), 256, 0, stream>>>(x + (long)ib * 3072, cw1, A1, C1, bufA);
    convmf_kernel<32, 32, 64, 1>
        <<<dim3(n * 4), 256, 0, stream>>>(bufA, wT2, A2, C2, bufB);
    convmf_kernel<16, 64, 128, 0>
        <<<dim3(n * 2), 256, 0, stream>>>(bufB, wT3, A3, C3, bufA);
    convmf_kernel<16, 128, 256, 2>
        <<<dim3(n * 4), 256, 0, stream>>>(bufA, wT4, A4, C4, feats + (long)ib * 256);
  }

  float* rsOut = out + 20480;
  heads2_kernel<<<dim3(32, 16), 256, 0, stream>>>(feats, gw1, gb1, gw2, gb2,
                                                  clsw, clsb, usage, logitsE, rsOut);
  sort_kernel<<<16, 1024, 0, stream>>>(rsOut, sortedIdx);
  routing_kernel<<<1, 1024, 0, stream>>>(sortedIdx, rsOut, out + 53248, dmask);
  combine_kernel<<<8, 256, 0, stream>>>(dmask, rsOut, logitsE, out);
}

// Round 4
// 1804.951 us; speedup vs baseline: 5.2221x; 1.8737x over previous
//
#include <hip/hip_runtime.h>

typedef __attribute__((ext_vector_type(8))) short short8;
typedef __attribute__((ext_vector_type(4))) float f32x4;

__device__ __forceinline__ unsigned short f2bf(float f) {
  unsigned u = __float_as_uint(f);
  unsigned r = (u + 0x7fffu + ((u >> 16) & 1u)) >> 16;
  return (unsigned short)r;
}
__device__ __forceinline__ float bf2f(unsigned short h) {
  return __uint_as_float(((unsigned)h) << 16);
}

// ---------------------------------------------------------------------------
__global__ __launch_bounds__(256) void bnprep_kernel(
    const float* __restrict__ g, const float* __restrict__ be,
    const float* __restrict__ m, const float* __restrict__ v,
    const float* __restrict__ b, float* __restrict__ A, float* __restrict__ C, int n)
{
  int i = blockIdx.x * 256 + threadIdx.x;
  if (i < n) {
    float s = g[i] / sqrtf(v[i] + 1e-5f);
    A[i] = s;
    C[i] = (b[i] - m[i]) * s + be[i];
  }
}

// Pre-pack conv weights into MFMA B-fragment order:
// unit = (s*NCB + cb)*NF + f ; halves addr = unit*1024 + plane*512 + lane*8 + j
// element = plane==0 ? hi : lo of W[co = f*16 + (lane&15)][ci = cb*32 + (lane>>4)*8 + j][k=s]
__global__ __launch_bounds__(256) void wprep2_kernel(
    const float* __restrict__ w, unsigned short* __restrict__ wPk, int CO, int CI)
{
  int NCB = CI / 32, NF = CO / 16;
  int total = 9 * NCB * NF * 64;
  int idx = blockIdx.x * 256 + threadIdx.x;
  if (idx >= total) return;
  int lane = idx & 63;
  int unit = idx >> 6;                  // (s*NCB + cb)*NF + f
  int f = unit % NF;
  int cb = (unit / NF) % NCB;
  int s = unit / (NF * NCB);
  int co = f * 16 + (lane & 15);
  int ci0 = cb * 32 + (lane >> 4) * 8;
  long base = (long)unit * 1024 + lane * 8;
  #pragma unroll
  for (int j = 0; j < 8; ++j) {
    float v = w[((long)co * CI + ci0 + j) * 9 + s];
    unsigned short h = f2bf(v);
    unsigned short l = f2bf(v - bf2f(h));
    wPk[base + j] = h;
    wPk[base + 512 + j] = l;
  }
}

// conv1: 3->32, 32x32, fp32 compute, emits channel-last split-bf16.
__global__ __launch_bounds__(256) void conv1_kernel(
    const float* __restrict__ in, const float* __restrict__ wgt,
    const float* __restrict__ Ap, const float* __restrict__ Cp,
    unsigned short* __restrict__ out)
{
  __shared__ alignas(16) float smem[3 * 432 + 864];
  const int tid = threadIdx.x;
  const int img = blockIdx.x;
  const int by = (blockIdx.y >> 1) * 16, bx = (blockIdx.y & 1) * 16;
  const int r0 = (tid & 63) >> 4, xx = tid & 15, cog = tid >> 6;

  float acc[4][8];
  #pragma unroll
  for (int i = 0; i < 4; ++i)
    #pragma unroll
    for (int j = 0; j < 8; ++j) acc[i][j] = 0.f;

  for (int e = tid; e < 972; e += 256) {
    int ci = e / 324, rem = e - ci * 324;
    int rr = rem / 18, cc = rem - rr * 18;
    int gy = by + rr - 1, gx = bx + cc - 1;
    float v = 0.f;
    if (gy >= 0 && gy < 32 && gx >= 0 && gx < 32)
      v = in[(long)img * 3072 + ci * 1024 + gy * 32 + gx];
    smem[ci * 432 + rr * 24 + cc] = v;
  }
  for (int e = tid; e < 864; e += 256) {
    int co = e & 31, rem = e >> 5;  // rem = ci*9+k
    smem[1296 + rem * 32 + co] = wgt[(long)co * 27 + rem];
  }
  __syncthreads();
  for (int ci = 0; ci < 3; ++ci) {
    #pragma unroll
    for (int k = 0; k < 9; ++k) {
      int ky = k / 3, kx = k - 3 * (k / 3);
      const float4* w4 = (const float4*)(smem + 1296 + (ci * 9 + k) * 32 + cog * 8);
      float4 w0 = w4[0], w1 = w4[1];
      #pragma unroll
      for (int i = 0; i < 4; ++i) {
        float iv = smem[ci * 432 + (r0 + 4 * i + ky) * 24 + xx + kx];
        acc[i][0] += iv * w0.x; acc[i][1] += iv * w0.y;
        acc[i][2] += iv * w0.z; acc[i][3] += iv * w0.w;
        acc[i][4] += iv * w1.x; acc[i][5] += iv * w1.y;
        acc[i][6] += iv * w1.z; acc[i][7] += iv * w1.w;
      }
    }
  }
  #pragma unroll
  for (int j = 0; j < 8; ++j) {
    int co = cog * 8 + j;
    float Ar = Ap[co], Cr = Cp[co];
    #pragma unroll
    for (int i = 0; i < 4; ++i) {
      float vv = fmaxf(acc[i][j] * Ar + Cr, 0.f);
      unsigned short h = f2bf(vv);
      unsigned short l = f2bf(vv - bf2f(h));
      long px = (long)img * 1024 + (by + r0 + 4 * i) * 32 + bx + xx;
      out[px * 64 + co] = h;
      out[px * 64 + 32 + co] = l;
    }
  }
}

// ---------------------------------------------------------------------------
// Split-bf16 MFMA conv v2: A tile in LDS (46.7 KB -> 3 blocks/CU), B read as
// pre-packed fragments straight from global (L1/L2-resident), coalesced
// epilogue via per-wave LDS transpose, XCD-chunked block swizzle.
template<int H, int CI, int CO, int MODE>
__global__ __launch_bounds__(256, 3) void convmf2_kernel(
    const unsigned short* __restrict__ actIn, const unsigned short* __restrict__ wPk,
    const float* __restrict__ Ap, const float* __restrict__ Cp,
    void* __restrict__ outP)
{
  constexpr int NCB = CI / 32;
  constexpr int TILES = (H == 32) ? 4 : 1;
  constexpr int COGN = CO / 64;
  constexpr int TPI = TILES * COGN;
  constexpr int PIX_IN = 2 * CI;
  constexpr int NF = CO / 16;
  __shared__ alignas(16) unsigned short smem[23328];   // 324 x 72 halves

  // bijective XCD-chunked swizzle (m204): sibling blocks share an XCD L2
  const int nwg = gridDim.x;
  const int orig = blockIdx.x;
  const int q = nwg >> 3, r = nwg & 7;
  const int xcd = orig & 7, pos = orig >> 3;
  const int bx = (xcd < r ? xcd * (q + 1) : r * (q + 1) + (xcd - r) * q) + pos;

  const int img = bx / TPI;
  const int sub = bx % TPI;
  const int tY0 = (H == 32) ? ((sub >> 1) & 1) * 16 : 0;
  const int tX0 = (H == 32) ? (sub & 1) * 16 : 0;
  const int coG = (H == 32) ? 0 : sub;

  const int tid = threadIdx.x;
  const int lane = tid & 63;
  const int lx = lane & 15;
  const int kg = lane >> 4;
  const int w = tid >> 6;

  f32x4 acc[4][4];
  #pragma unroll
  for (int i = 0; i < 4; ++i)
    #pragma unroll
    for (int j = 0; j < 4; ++j) acc[i][j] = (f32x4){0.f, 0.f, 0.f, 0.f};

  for (int cb = 0; cb < NCB; ++cb) {
    if (cb) __syncthreads();
    // stage A tile (halo, zero-padded), direct global->LDS copy
    for (int t2 = tid; t2 < 2592; t2 += 256) {
      int lp = t2 >> 3, c = t2 & 7;
      int ry = lp / 18, rx = lp - ry * 18;
      int gy = tY0 + ry - 1, gx = tX0 + rx - 1;
      float4 v = (float4){0.f, 0.f, 0.f, 0.f};
      if (gy >= 0 && gy < H && gx >= 0 && gx < H) {
        int coff = (c < 4) ? (cb * 32 + c * 8) : (CI + cb * 32 + (c - 4) * 8);
        v = *(const float4*)(actIn + ((long)img * H * H + gy * H + gx) * PIX_IN + coff);
      }
      *(float4*)(smem + lp * 72 + c * 8) = v;
    }
    __syncthreads();

    for (int s = 0; s < 9; ++s) {
      const int ky = s / 3, kx = s - 3 * (s / 3);
      const long ub = ((long)(s * NCB + cb) * NF + coG * 4) * 1024 + lane * 8;
      short8 bh[4], bl[4];
      #pragma unroll
      for (int nf = 0; nf < 4; ++nf) {
        bh[nf] = *(const short8*)(wPk + ub + nf * 1024);
        bl[nf] = *(const short8*)(wPk + ub + nf * 1024 + 512);
      }
      #pragma unroll
      for (int mf = 0; mf < 4; ++mf) {
        const unsigned short* ap = smem + ((w * 4 + mf + ky) * 18 + lx + kx) * 72 + kg * 8;
        short8 ah = *(const short8*)ap;
        short8 al = *(const short8*)(ap + 32);
        #pragma unroll
        for (int nf = 0; nf < 4; ++nf)
          acc[mf][nf] = __builtin_amdgcn_mfma_f32_16x16x32_bf16(ah, bh[nf], acc[mf][nf], 0, 0, 0);
        #pragma unroll
        for (int nf = 0; nf < 4; ++nf)
          acc[mf][nf] = __builtin_amdgcn_mfma_f32_16x16x32_bf16(ah, bl[nf], acc[mf][nf], 0, 0, 0);
        #pragma unroll
        for (int nf = 0; nf < 4; ++nf)
          acc[mf][nf] = __builtin_amdgcn_mfma_f32_16x16x32_bf16(al, bh[nf], acc[mf][nf], 0, 0, 0);
      }
    }
  }
  __syncthreads();   // A region now reusable as epilogue staging

  float ArV[4], CrV[4];
  #pragma unroll
  for (int nf = 0; nf < 4; ++nf) {
    int co = coG * 64 + nf * 16 + lx;
    ArV[nf] = Ap[co]; CrV[nf] = Cp[co];
  }

  if (MODE == 0) {
    // plain store, coalesced via per-wave 4KB transpose slice
    unsigned short* outA = (unsigned short*)outP;
    unsigned short* slice = smem + w * 2048;
    #pragma unroll
    for (int mf = 0; mf < 4; ++mf) {
      int y = w * 4 + mf;
      #pragma unroll
      for (int rr = 0; rr < 4; ++rr) {
        int x = 4 * kg + rr;
        #pragma unroll
        for (int nf = 0; nf < 4; ++nf) {
          float vv = fmaxf(acc[mf][nf][rr] * ArV[nf] + CrV[nf], 0.f);
          unsigned short h = f2bf(vv);
          unsigned short l = f2bf(vv - bf2f(h));
          slice[(x * 2 + 0) * 64 + nf * 16 + lx] = h;
          slice[(x * 2 + 1) * 64 + nf * 16 + lx] = l;
        }
      }
      #pragma unroll
      for (int v = 0; v < 4; ++v) {
        int hoff = lane * 8 + v * 512;
        int x = hoff >> 7, rem = hoff & 127;
        int seg = rem >> 6, inner = rem & 63;
        short8 d = *(const short8*)(slice + hoff);
        *(short8*)(outA + ((long)img * 256 + y * 16 + x) * (2 * CO)
                   + seg * CO + coG * 64 + inner) = d;
      }
    }
  } else if (MODE == 1) {
    // fused 2x2 maxpool store, coalesced via per-wave 2KB transpose slice
    unsigned short* outA = (unsigned short*)outP;
    unsigned short* slice = smem + w * 1024;
    #pragma unroll
    for (int mfp = 0; mfp < 2; ++mfp) {
      int oy = (tY0 >> 1) + w * 2 + mfp;
      #pragma unroll
      for (int rp = 0; rp < 2; ++rp) {
        int oxl = 2 * kg + rp;
        #pragma unroll
        for (int nf = 0; nf < 4; ++nf) {
          float v0 = fmaxf(fmaxf(acc[2 * mfp][nf][2 * rp], acc[2 * mfp][nf][2 * rp + 1]),
                           fmaxf(acc[2 * mfp + 1][nf][2 * rp], acc[2 * mfp + 1][nf][2 * rp + 1]));
          float vv = fmaxf(v0 * ArV[nf] + CrV[nf], 0.f);
          unsigned short h = f2bf(vv);
          unsigned short l = f2bf(vv - bf2f(h));
          slice[(oxl * 2 + 0) * 64 + nf * 16 + lx] = h;
          slice[(oxl * 2 + 1) * 64 + nf * 16 + lx] = l;
        }
      }
      #pragma unroll
      for (int v = 0; v < 2; ++v) {
        int hoff = lane * 8 + v * 512;
        int oxl = hoff >> 7, rem = hoff & 127;
        int seg = rem >> 6, inner = rem & 63;
        short8 d = *(const short8*)(slice + hoff);
        *(short8*)(outA + ((long)img * 256 + oy * 16 + (tX0 >> 1) + oxl) * 128
                   + seg * 64 + inner) = d;
      }
    }
  } else {
    // pool + BN/ReLU + global average -> feats[img][coG*64 + co] (fp32)
    float psum[4] = {0.f, 0.f, 0.f, 0.f};
    #pragma unroll
    for (int nf = 0; nf < 4; ++nf) {
      #pragma unroll
      for (int mfp = 0; mfp < 2; ++mfp) {
        #pragma unroll
        for (int rp = 0; rp < 2; ++rp) {
          float v = fmaxf(fmaxf(acc[2 * mfp][nf][2 * rp], acc[2 * mfp][nf][2 * rp + 1]),
                          fmaxf(acc[2 * mfp + 1][nf][2 * rp], acc[2 * mfp + 1][nf][2 * rp + 1]));
          psum[nf] += fmaxf(v * ArV[nf] + CrV[nf], 0.f);
        }
      }
    }
    #pragma unroll
    for (int nf = 0; nf < 4; ++nf) {
      psum[nf] += __shfl_xor(psum[nf], 16);
      psum[nf] += __shfl_xor(psum[nf], 32);
    }
    __syncthreads();
    float* sR = (float*)smem;
    if (kg == 0) {
      #pragma unroll
      for (int nf = 0; nf < 4; ++nf) sR[w * 64 + nf * 16 + lx] = psum[nf];
    }
    __syncthreads();
    if (tid < 64) {
      float s = sR[tid] + sR[64 + tid] + sR[128 + tid] + sR[192 + tid];
      ((float*)outP)[(long)img * 256 + coG * 64 + tid] = s * (1.f / 64.f);
    }
  }
}

// ---------------------------------------------------------------------------
// heads / sort / routing / combine (unchanged)
__global__ __launch_bounds__(256) void heads2_kernel(
    const float* __restrict__ feats, const float* __restrict__ gw1,
    const float* __restrict__ gb1, const float* __restrict__ gw2,
    const float* __restrict__ gb2, const float* __restrict__ clsw,
    const float* __restrict__ clsb, const float* __restrict__ usage,
    float* __restrict__ logits_e, float* __restrict__ rs_out)
{
  __shared__ float sF[64 * 257];
  __shared__ float sLg[4 * 64 * 10];
  __shared__ float sRed[4 * 64];
  const int tid = threadIdx.x;
  const int b0 = blockIdx.x * 64;
  const int e  = blockIdx.y;

  for (int idx = tid; idx < 64 * 64; idx += 256) {
    int t = idx >> 6, dg = idx & 63;
    float4 v = ((const float4*)(feats + (long)(b0 + t) * 256))[dg];
    float* p = sF + t * 257 + dg * 4;
    p[0] = v.x; p[1] = v.y; p[2] = v.z; p[3] = v.w;
  }
  __syncthreads();

  const int t  = tid & 63;
  const int hw = __builtin_amdgcn_readfirstlane(tid >> 6);

  {
    float acc[10];
    #pragma unroll
    for (int c = 0; c < 10; ++c) acc[c] = 0.f;
    const float* fp = sF + t * 257 + hw * 64;
    const float* cw = clsw + (long)e * 2560 + hw * 64;
    for (int dd = 0; dd < 64; ++dd) {
      float f = fp[dd];
      #pragma unroll
      for (int c = 0; c < 10; ++c) acc[c] += f * cw[c * 256 + dd];
    }
    #pragma unroll
    for (int c = 0; c < 10; ++c) sLg[(hw * 64 + t) * 10 + c] = acc[c];
  }
  {
    float gacc[32];
    #pragma unroll
    for (int j = 0; j < 32; ++j) gacc[j] = 0.f;
    const float* wb = gw1 + ((long)e * 256) * 128 + hw * 32;
    const float* fp = sF + t * 257;
    for (int d = 0; d < 256; ++d) {
      float f = fp[d];
      const float4* w4 = (const float4*)(wb + (long)d * 128);
      #pragma unroll
      for (int qq = 0; qq < 8; ++qq) {
        float4 wv = w4[qq];
        gacc[4 * qq + 0] += f * wv.x; gacc[4 * qq + 1] += f * wv.y;
        gacc[4 * qq + 2] += f * wv.z; gacc[4 * qq + 3] += f * wv.w;
      }
    }
    float s = 0.f;
    const float* b1 = gb1 + e * 128 + hw * 32;
    const float* w2 = gw2 + e * 128 + hw * 32;
    #pragma unroll
    for (int j = 0; j < 32; ++j) s += fmaxf(gacc[j] + b1[j], 0.f) * w2[j];
    sRed[hw * 64 + t] = s;
  }
  __syncthreads();

  if (tid < 64) {
    float es = (sRed[t] + sRed[64 + t] + sRed[128 + t] + sRed[192 + t] + gb2[e]) * 0.5f;
    float lg[10];
    #pragma unroll
    for (int c = 0; c < 10; ++c)
      lg[c] = sLg[t * 10 + c] + sLg[(64 + t) * 10 + c]
            + sLg[(128 + t) * 10 + c] + sLg[(192 + t) * 10 + c] + clsb[e * 10 + c];
    float mx = lg[0];
    #pragma unroll
    for (int c = 1; c < 10; ++c) mx = fmaxf(mx, lg[c]);
    float S = 0.f, ps[10];
    #pragma unroll
    for (int c = 0; c < 10; ++c) { ps[c] = expf(lg[c] - mx); S += ps[c]; }
    float inv = 1.f / S, ent = 0.f;
    #pragma unroll
    for (int c = 0; c < 10; ++c) { float p = ps[c] * inv; ent -= p * logf(fmaxf(p, 1e-12f)); }
    float rsv = 0.6f * es + 0.4f * (-ent) - 2.0f * usage[e];
    rs_out[(long)(b0 + t) * 16 + e] = rsv;
    #pragma unroll
    for (int c = 0; c < 10; ++c)
      logits_e[((long)(b0 + t) * 16 + e) * 10 + c] = lg[c];
  }
}

__global__ __launch_bounds__(1024) void sort_kernel(
    const float* __restrict__ rs, unsigned* __restrict__ sortedIdx)
{
  __shared__ unsigned long long sk[2048];
  const int e = blockIdx.x;
  const unsigned tid = threadIdx.x;
  for (int i = tid; i < 2048; i += 1024) {
    float f = rs[(long)i * 16 + e];
    unsigned u = __float_as_uint(f);
    u ^= (u >> 31) ? 0xFFFFFFFFu : 0x80000000u;
    sk[i] = ((unsigned long long)(~u) << 32) | (unsigned)i;
  }
  for (unsigned k = 2; k <= 2048; k <<= 1) {
    for (unsigned j = k >> 1; j > 0; j >>= 1) {
      __syncthreads();
      unsigned i = ((tid & ~(j - 1)) << 1) | (tid & (j - 1));
      unsigned p = i | j;
      bool asc = ((i & k) == 0);
      unsigned long long a = sk[i], b = sk[p];
      if ((a > b) == asc) { sk[i] = b; sk[p] = a; }
    }
  }
  __syncthreads();
  for (int i = tid; i < 2048; i += 1024)
    sortedIdx[(long)e * 2048 + i] = (unsigned)(sk[i] & 0xFFFFFFFFull);
}

__global__ __launch_bounds__(1024) void routing_kernel(
    const unsigned* __restrict__ sortedIdx, const float* __restrict__ rs,
    float* __restrict__ Dout, unsigned* __restrict__ dmaskOut)
{
  __shared__ unsigned char sAvail[2048];
  __shared__ unsigned sDm[2048];
  __shared__ int sLoads[16];
  __shared__ int sWaveCnt[16];
  __shared__ int sNtc, sVC;
  const int tid = threadIdx.x;
  const int lane = tid & 63, wave = tid >> 6;
  for (int i = tid; i < 2048; i += 1024) { sAvail[i] = 1; sDm[i] = 0; }
  if (tid < 16) sLoads[tid] = 0;
  if (tid == 0) sVC = 2048;
  __syncthreads();
  for (int it = 0; it < 3; ++it) {
    for (int j = 0; j < 16; ++j) {
      if (tid == 0) {
        int rc = 256 - sLoads[j]; if (rc < 0) rc = 0;
        int vc = sVC, ntc = 0;
        if (rc > 0 && vc > 0) {
          int a = rc < vc ? rc : vc;
          int b2 = vc < 102 ? vc : 102;
          ntc = a > b2 ? a : b2;
        }
        sNtc = ntc; sLoads[j] += ntc; sVC -= ntc;
      }
      __syncthreads();
      const int ntc = sNtc;
      if (ntc > 0) {
        int base = 0;
        for (int p = 0; p < 2; ++p) {
          int i = p * 1024 + tid;
          unsigned tok = sortedIdx[(long)j * 2048 + i];
          int fl = sAvail[tok] ? 1 : 0;
          unsigned long long bm = __ballot(fl);
          if (lane == 0) sWaveCnt[wave] = __popcll(bm);
          __syncthreads();
          int off = base;
          for (int w = 0; w < wave; ++w) off += sWaveCnt[w];
          int pre = off + __popcll(bm & ((1ull << lane) - 1ull));
          if (fl && pre < ntc) { sAvail[tok] = 0; sDm[tok] |= (1u << j); }
          int tot = base;
          for (int w = 0; w < 16; ++w) tot += sWaveCnt[w];
          base = tot;
          __syncthreads();
        }
      }
      __syncthreads();
    }
  }
  if (tid == 0 && sVC > 0) {
    for (int i = 0; i < 2048; ++i) {
      if (!sAvail[i]) continue;
      float s0 = -3.4e38f, s1 = s0, s2 = s0; int e0 = 0, e1 = 0, e2 = 0;
      for (int e = 0; e < 16; ++e) {
        float s = rs[i * 16 + e];
        if (s > s0)      { s2 = s1; e2 = e1; s1 = s0; e1 = e0; s0 = s; e0 = e; }
        else if (s > s1) { s2 = s1; e2 = e1; s1 = s;  e1 = e; }
        else if (s > s2) { s2 = s;  e2 = e; }
      }
      int best = e0, bl = sLoads[e0];
      if (sLoads[e1] < bl) { best = e1; bl = sLoads[e1]; }
      if (sLoads[e2] < bl) { best = e2; bl = sLoads[e2]; }
      sDm[i] |= (1u << best);
      sLoads[best] += 1;
    }
  }
  __syncthreads();
  for (int idx = tid; idx < 2048 * 16; idx += 1024) {
    int tok = idx >> 4, e = idx & 15;
    Dout[idx] = ((sDm[tok] >> e) & 1u) ? 1.0f : 0.0f;
  }
  for (int i = tid; i < 2048; i += 1024) dmaskOut[i] = sDm[i];
}

__global__ __launch_bounds__(256) void combine_kernel(
    const unsigned* __restrict__ dmask, const float* __restrict__ rs,
    const float* __restrict__ L, float* __restrict__ out)
{
  int i = blockIdx.x * 256 + threadIdx.x;
  if (i >= 2048) return;
  unsigned dm = dmask[i];
  float r[16];
  #pragma unroll
  for (int e = 0; e < 16; ++e) r[e] = rs[i * 16 + e];
  float mx = -3.4e38f;
  #pragma unroll
  for (int e = 0; e < 16; ++e) {
    float v = ((dm >> e) & 1u) ? r[e] : 0.0f;
    mx = fmaxf(mx, v);
  }
  float w[16], S = 0.f;
  #pragma unroll
  for (int e = 0; e < 16; ++e) {
    w[e] = ((dm >> e) & 1u) ? expf(r[e] - mx) : 0.0f;
    S += w[e];
  }
  float inv = 1.f / S;
  #pragma unroll
  for (int c = 0; c < 10; ++c) {
    float a = 0.f;
    #pragma unroll
    for (int e = 0; e < 16; ++e) a += w[e] * L[((long)i * 16 + e) * 10 + c];
    out[i * 10 + c] = a * inv;
  }
}

// ---------------------------------------------------------------------------
extern "C" void kernel_launch(void* const* d_in, const int* in_sizes, int n_in,
                              void* d_out, int out_size, void* d_ws, size_t ws_size,
                              hipStream_t stream)
{
  const float* x    = (const float*)d_in[0];
  const float* cw1  = (const float*)d_in[1];
  const float* cb1  = (const float*)d_in[2];
  const float* g1   = (const float*)d_in[3];
  const float* be1  = (const float*)d_in[4];
  const float* m1   = (const float*)d_in[5];
  const float* v1   = (const float*)d_in[6];
  const float* cw2  = (const float*)d_in[7];
  const float* cb2  = (const float*)d_in[8];
  const float* g2   = (const float*)d_in[9];
  const float* be2  = (const float*)d_in[10];
  const float* m2   = (const float*)d_in[11];
  const float* v2   = (const float*)d_in[12];
  const float* cw3  = (const float*)d_in[13];
  const float* cb3  = (const float*)d_in[14];
  const float* g3   = (const float*)d_in[15];
  const float* be3  = (const float*)d_in[16];
  const float* m3   = (const float*)d_in[17];
  const float* v3   = (const float*)d_in[18];
  const float* cw4  = (const float*)d_in[19];
  const float* cb4  = (const float*)d_in[20];
  const float* g4   = (const float*)d_in[21];
  const float* be4  = (const float*)d_in[22];
  const float* m4   = (const float*)d_in[23];
  const float* v4   = (const float*)d_in[24];
  const float* gw1  = (const float*)d_in[25];
  const float* gb1  = (const float*)d_in[26];
  const float* gw2  = (const float*)d_in[27];
  const float* gb2  = (const float*)d_in[28];
  const float* clsw = (const float*)d_in[29];
  const float* clsb = (const float*)d_in[30];
  const float* usage = (const float*)d_in[31];

  float* out = (float*)d_out;
  float* ws  = (float*)d_ws;

  float* A1 = ws + 0;   float* C1 = ws + 32;
  float* A2 = ws + 64;  float* C2 = ws + 128;
  float* A3 = ws + 192; float* C3 = ws + 320;
  float* A4 = ws + 448; float* C4 = ws + 704;
  float* feats   = ws + 1024;                       // 2048*256
  float* logitsE = ws + 525312;                     // 2048*16*10
  unsigned* sortedIdx = (unsigned*)(ws + 852992);   // 16*2048
  unsigned* dmask     = (unsigned*)(ws + 885760);   // 2048
  unsigned short* wPk2 = (unsigned short*)(ws + 887808);   // 36 units  * 1024 halves
  unsigned short* wPk3 = (unsigned short*)(ws + 906240);   // 144 units * 1024
  unsigned short* wPk4 = (unsigned short*)(ws + 979968);   // 576 units * 1024
  const long bufBase = 1274880;

  long wsFloats = (long)(ws_size / 4);
  long availF = wsFloats - bufBase;
  long chunkL = availF / 49152;   // per-img: bufA 32768 f + bufB 16384 f
  int chunk = (int)(chunkL < 1 ? 1 : (chunkL > 2048 ? 2048 : chunkL));

  bnprep_kernel<<<1, 256, 0, stream>>>(g1, be1, m1, v1, cb1, A1, C1, 32);
  bnprep_kernel<<<1, 256, 0, stream>>>(g2, be2, m2, v2, cb2, A2, C2, 64);
  bnprep_kernel<<<1, 256, 0, stream>>>(g3, be3, m3, v3, cb3, A3, C3, 128);
  bnprep_kernel<<<1, 256, 0, stream>>>(g4, be4, m4, v4, cb4, A4, C4, 256);
  wprep2_kernel<<<(2304 + 255) / 256, 256, 0, stream>>>(cw2, wPk2, 64, 32);
  wprep2_kernel<<<(9216 + 255) / 256, 256, 0, stream>>>(cw3, wPk3, 128, 64);
  wprep2_kernel<<<(36864 + 255) / 256, 256, 0, stream>>>(cw4, wPk4, 256, 128);

  unsigned short* bufA = (unsigned short*)(ws + bufBase);
  unsigned short* bufB = bufA + (long)chunk * 65536;

  for (int ib = 0; ib < 2048; ib += chunk) {
    int n = 2048 - ib; if (n > chunk) n = chunk;
    conv1_kernel<<<dim3(n, 4), 256, 0, stream>>>(x + (long)ib * 3072, cw1, A1, C1, bufA);
    convmf2_kernel<32, 32, 64, 1>
        <<<dim3(n * 4), 256, 0, stream>>>(bufA, wPk2, A2, C2, bufB);
    convmf2_kernel<16, 64, 128, 0>
        <<<dim3(n * 2), 256, 0, stream>>>(bufB, wPk3, A3, C3, bufA);
    convmf2_kernel<16, 128, 256, 2>
        <<<dim3(n * 4), 256, 0, stream>>>(bufA, wPk4, A4, C4, feats + (long)ib * 256);
  }

  float* rsOut = out + 20480;
  heads2_kernel<<<dim3(32, 16), 256, 0, stream>>>(feats, gw1, gb1, gw2, gb2,
                                                  clsw, clsb, usage, logitsE, rsOut);
  sort_kernel<<<16, 1024, 0, stream>>>(rsOut, sortedIdx);
  routing_kernel<<<1, 1024, 0, stream>>>(sortedIdx, rsOut, out + 53248, dmask);
  combine_kernel<<<8, 256, 0, stream>>>(dmask, rsOut, logitsE, out);
}